// Round 12
// baseline (2686.288 us; speedup 1.0000x reference)
//
#include <hip/hip_runtime.h>
#include <math.h>

// ---------------- configuration ----------------
#define NHEAD 8
#define HID   768
#define FFND  3072
#define EOUTD 256
#define BATCH 1024
#define TOK   (BATCH*64)   // 65536

#define EPI_RESF  1
#define EPI_RESB  2
#define EPI_GELU  4
#define EPI_OUTF  8
#define EPI_OUTB  16

typedef __attribute__((ext_vector_type(8))) short short8;   // 8 x bf16
typedef __attribute__((ext_vector_type(4))) float f32x4;    // MFMA C/D

#define AS1 __attribute__((address_space(1)))
#define AS3 __attribute__((address_space(3)))

__device__ __forceinline__ void async16(const void* g, void* l) {
  __builtin_amdgcn_global_load_lds(
      (AS1 unsigned int*)(unsigned long long)g,
      (AS3 unsigned int*)(unsigned int)(unsigned long long)l,
      16, 0, 0);
}

// opaque LDS read: invisible to the waitcnt pass (no auto vmcnt(0) vs LDS-DMA).
// Ordering vs barriers/waits: volatile-asm program order. Data readiness:
// guaranteed by the staging ring's counted vmcnt + barriers.
__device__ __forceinline__ short8 dsr16(const unsigned short* p) {
  short8 r;
  const unsigned a = (unsigned)(unsigned long long)p;   // low 32b = LDS byte offset
  asm volatile("ds_read_b128 %0, %1" : "=v"(r) : "v"(a));
  return r;
}

__device__ __forceinline__ float bf2f(unsigned short u) {
  union { unsigned int i; float f; } c; c.i = ((unsigned int)u) << 16; return c.f;
}
__device__ __forceinline__ unsigned short f2bf(float f) {
  union { float f; unsigned int i; } c; c.f = f;
  unsigned int x = c.i + 0x7fffu + ((c.i >> 16) & 1u);   // RNE
  return (unsigned short)(x >> 16);
}
__device__ __forceinline__ float wsum(float v) {
#pragma unroll
  for (int o = 32; o > 0; o >>= 1) v += __shfl_xor(v, o);
  return v;
}
// GELU with fast erf (Abramowitz-Stegun 7.1.26, |err| < 1.5e-7)
__device__ __forceinline__ float gelu_f(float v) {
  const float z = fabsf(v) * 0.70710678118654752f;
  const float t = 1.0f / (1.0f + 0.3275911f * z);
  const float poly = t * (0.254829592f + t * (-0.284496736f +
                     t * (1.421413741f + t * (-1.453152027f + t * 1.061405429f))));
  float erfv = 1.0f - poly * __expf(-z * z);
  erfv = (v < 0.f) ? -erfv : erfv;
  return 0.5f * v * (1.0f + erfv);
}

// Bare barrier / counted waits: NO "memory" clobber (a memory-clobbering
// INLINEASM makes LLVM's waitcnt pass insert vmcnt(0) drains while LDS-DMA
// is outstanding — that was R4's 27% MfmaUtil). All K-loop memory ops are
// volatile asm or side-effecting builtins, so program order is preserved
// without a compiler fence.
#define SBAR() __builtin_amdgcn_s_barrier()
#define WAITV(n) asm volatile("s_waitcnt vmcnt(" #n ")")
#define LGKM0() { asm volatile("s_waitcnt lgkmcnt(0)"); __builtin_amdgcn_sched_barrier(0); }

// ---------------- GEMM 128x128 (proven workhorse) ----------------
template<int EPI>
__global__ __launch_bounds__(256, 3) void gemm_k(
    const unsigned short* __restrict__ A, const unsigned short* __restrict__ Wt,
    const float* __restrict__ bias,
    const float* __restrict__ residF, const unsigned short* __restrict__ residB,
    float* __restrict__ outF, unsigned short* __restrict__ outB,
    int M, int N, int K)
{
  __shared__ unsigned short lA[128 * 64];
  __shared__ unsigned short lB[128 * 64];
  const int tid  = threadIdx.x;

  const int nT  = N >> 7;
  const int per = gridDim.x >> 3;
  const int tile = (blockIdx.x & 7) * per + (blockIdx.x >> 3);
  int m_idx = tile / nT;
  int n_idx = tile - m_idx * nT;
  if (m_idx & 1) n_idx = nT - 1 - n_idx;
  const int n0 = n_idx * 128;
  const int m0 = m_idx * 128;

  const int lane = tid & 63;
  const int wid  = tid >> 6;
  const int wm   = wid & 1, wn = wid >> 1;
  const int m16  = lane & 15, quad = lane >> 4;

  f32x4 zero = {0.0f, 0.0f, 0.0f, 0.0f};
  f32x4 acc[4][4];
#pragma unroll
  for (int i = 0; i < 4; i++)
#pragma unroll
    for (int j = 0; j < 4; j++) acc[i][j] = zero;

  long aoff[4], boff[4];
#pragma unroll
  for (int j = 0; j < 4; j++) {
    const int L = tid + j * 256;
    const int row = L >> 3;
    const int kc  = (L & 7) ^ (row & 7);
    aoff[j] = (long)(m0 + row) * K + kc * 8;
    boff[j] = (long)(n0 + row) * K + kc * 8;
  }

  for (int k0 = 0; k0 < K; k0 += 64) {
#pragma unroll
    for (int j = 0; j < 4; j++)
      async16(A + aoff[j] + k0, lA + (size_t)(j * 256 + wid * 64) * 8);
#pragma unroll
    for (int j = 0; j < 4; j++)
      async16(Wt + boff[j] + k0, lB + (size_t)(j * 256 + wid * 64) * 8);
    __syncthreads();
#pragma unroll
    for (int s = 0; s < 2; s++) {
      short8 af[4], bfr[4];
#pragma unroll
      for (int mi = 0; mi < 4; mi++) {
        const int row = wm * 64 + mi * 16 + m16;
        const int kc  = (s * 4 + quad) ^ (row & 7);
        af[mi] = *(const short8*)(lA + row * 64 + kc * 8);
      }
#pragma unroll
      for (int ni = 0; ni < 4; ni++) {
        const int row = wn * 64 + ni * 16 + m16;
        const int kc  = (s * 4 + quad) ^ (row & 7);
        bfr[ni] = *(const short8*)(lB + row * 64 + kc * 8);
      }
#pragma unroll
      for (int mi = 0; mi < 4; mi++)
#pragma unroll
        for (int ni = 0; ni < 4; ni++)
          acc[mi][ni] = __builtin_amdgcn_mfma_f32_16x16x32_bf16(bfr[ni], af[mi], acc[mi][ni], 0, 0, 0);
    }
    __syncthreads();
  }

#pragma unroll
  for (int mi = 0; mi < 4; mi++) {
    const int m = m0 + wm * 64 + mi * 16 + m16;
    const long rb = (long)m * N;
#pragma unroll
    for (int ni = 0; ni < 4; ni++) {
      const int nb = n0 + wn * 64 + ni * 16 + quad * 4;
      f32x4 v = acc[mi][ni];
      const f32x4 bi = *(const f32x4*)(bias + nb);
#pragma unroll
      for (int r = 0; r < 4; r++) v[r] += bi[r];
      if (EPI & EPI_RESF) {
        const f32x4 rf = *(const f32x4*)(residF + rb + nb);
#pragma unroll
        for (int r = 0; r < 4; r++) v[r] += rf[r];
      }
      if (EPI & EPI_RESB) {
        const unsigned long long rv = *(const unsigned long long*)(residB + rb + nb);
#pragma unroll
        for (int r = 0; r < 4; r++) v[r] += bf2f((unsigned short)(rv >> (16 * r)));
      }
      if (EPI & EPI_GELU) {
#pragma unroll
        for (int r = 0; r < 4; r++) v[r] = gelu_f(v[r]);
      }
      if (EPI & EPI_OUTF) *(f32x4*)(outF + rb + nb) = v;
      if (EPI & EPI_OUTB) {
        unsigned long long o = 0;
#pragma unroll
        for (int r = 0; r < 4; r++) o |= (unsigned long long)f2bf(v[r]) << (16 * r);
        *(unsigned long long*)(outB + rb + nb) = o;
      }
    }
  }
}

// ---------------- GEMM 256x256, 8-phase counted-vmcnt, asm-opaque K-loop ----------------
// Same verified staging ring as R4 (passed verification); ONLY the read
// mechanism and fences changed:
//  - fragment reads via inline-asm ds_read_b128 (waitcnt pass can't see them)
//  - bare s_barrier, bare counted vmcnt (no "memory" clobbers anywhere)
//  - explicit lgkmcnt(0)+sched_barrier(0) before each MFMA cluster (rule #18)
// RING (reader table: A0:p1+p3  A1:p5+p7  B0:p1+p2  B1:p5+p6):
//   p1:A1h0(t1)  p2:A1h1(t1)  p3:B0h0(t+2)  p4:B0h1(t+2)+WAITV(4)
//   p5:A0h0(t+2) p6:A0h1(t+2) p7:B1h0(t+3)  p8:B1h1(t+3)+WAITV(4)
// At p4: 12 outstanding; vmcnt(4) lands the 8 oldest = ALL of buf1/t1.
// Symmetric at p8 for buf0/t+2. WAR safety without drains: each slot's stage
// issues >=1 phase after its last reader's lgkmcnt(0) (inside that phase's
// mmaq, between the two barriers).
template<int EPI>
__global__ __launch_bounds__(512, 2) void gemm256_k(
    const unsigned short* __restrict__ A, const unsigned short* __restrict__ Wt,
    const float* __restrict__ bias,
    const float* __restrict__ residF, const unsigned short* __restrict__ residB,
    float* __restrict__ outF, unsigned short* __restrict__ outB,
    int M, int N, int K)
{
  extern __shared__ unsigned short lds[];
  unsigned short* lA = lds;           // [2][256*64]
  unsigned short* lB = lds + 32768;   // [2][256*64]

  const int tid  = threadIdx.x;
  const int lane = tid & 63;
  const int wid  = tid >> 6;

  const int nT  = N >> 8;
  const int per = gridDim.x >> 3;
  const int tile = (blockIdx.x & 7) * per + (blockIdx.x >> 3);
  int m_idx = tile / nT;
  int n_idx = tile - m_idx * nT;
  if (m_idx & 1) n_idx = nT - 1 - n_idx;
  const int m0 = m_idx << 8, n0 = n_idx << 8;

  const int wm = wid >> 2, wn = wid & 3;          // wave grid 2(M) x 4(N)
  const int m16 = lane & 15, quad = lane >> 4;

  // staging constants (LDS linear; swizzle applied on GLOBAL source)
  const int r_lo = lane >> 3;
  const int kcg  = (lane & 7) ^ r_lo;
  long aoffj[2], boffj[2];
  int  ldsoj[2];
#pragma unroll
  for (int j = 0; j < 2; ++j) {
    const int rr = (j * 8 + wid) * 8 + r_lo;      // row within 128-row half-tile
    aoffj[j] = (long)(m0 + rr) * K + kcg * 8;
    boffj[j] = (long)(n0 + rr) * K + kcg * 8;
    ldsoj[j] = (j * 8 + wid) * 512;               // elements within half
  }

  auto stA = [&](int c, int hh, int t) {
    async16(A + aoffj[0] + (long)hh * 128 * K + t * 64, lA + c * 16384 + hh * 8192 + ldsoj[0]);
    async16(A + aoffj[1] + (long)hh * 128 * K + t * 64, lA + c * 16384 + hh * 8192 + ldsoj[1]);
  };
  auto stB = [&](int c, int hh, int t) {
    async16(Wt + boffj[0] + (long)hh * 128 * K + t * 64, lB + c * 16384 + hh * 8192 + ldsoj[0]);
    async16(Wt + boffj[1] + (long)hh * 128 * K + t * 64, lB + c * 16384 + hh * 8192 + ldsoj[1]);
  };

  // fragment reads (XOR-swizzled)
  const int xsw = m16 & 7;
  const int kx0 = ((0 + quad) ^ xsw) * 8;
  const int kx1 = ((4 + quad) ^ xsw) * 8;

  f32x4 zero = {0.f, 0.f, 0.f, 0.f};
  f32x4 acc[8][4];
#pragma unroll
  for (int i = 0; i < 8; i++)
#pragma unroll
    for (int j = 0; j < 4; j++) acc[i][j] = zero;

  short8 af[4][2], bf[4][2];
  auto ldA = [&](int c, int mh) {
#pragma unroll
    for (int mi = 0; mi < 4; ++mi) {
      const unsigned short* base = lA + c * 16384 + (wm * 128 + (mh * 4 + mi) * 16 + m16) * 64;
      af[mi][0] = dsr16(base + kx0);
      af[mi][1] = dsr16(base + kx1);
    }
  };
  auto ldB = [&](int c, int nh) {
#pragma unroll
    for (int nn = 0; nn < 2; ++nn) {
      const unsigned short* base = lB + c * 16384 + (wn * 64 + (nh * 2 + nn) * 16 + m16) * 64;
      bf[nh * 2 + nn][0] = dsr16(base + kx0);
      bf[nh * 2 + nn][1] = dsr16(base + kx1);
    }
  };
  auto mmaq = [&](int mh, int nh) {
    LGKM0();
    __builtin_amdgcn_s_setprio(1);
#pragma unroll
    for (int ks = 0; ks < 2; ++ks)
#pragma unroll
      for (int mi = 0; mi < 4; ++mi)
#pragma unroll
        for (int nn = 0; nn < 2; ++nn)
          acc[mh * 4 + mi][nh * 2 + nn] = __builtin_amdgcn_mfma_f32_16x16x32_bf16(
              bf[nh * 2 + nn][ks], af[mi][ks], acc[mh * 4 + mi][nh * 2 + nn], 0, 0, 0);
    __builtin_amdgcn_s_setprio(0);
  };

  const int NI = K >> 7;   // 2 K-tiles per iteration

  // prologue: t0 {Ah0,Ah1,Bh0,Bh1} + t1 {Bh0,Bh1} = 12 loads; WAITV(4) lands t0.
  stA(0, 0, 0); stA(0, 1, 0); stB(0, 0, 0); stB(0, 1, 0);
  stB(1, 0, 1); stB(1, 1, 1);
  WAITV(4);
  SBAR();

  for (int i = 0; i < NI - 1; ++i) {
    const int t1 = 2 * i + 1, s0 = 2 * i + 2, s1 = 2 * i + 3;
    // p1 (t even, m0n0)
    ldA(0, 0); ldB(0, 0);
    stA(1, 0, t1);
    SBAR(); mmaq(0, 0); SBAR();
    // p2 (m0n1)
    ldB(0, 1);
    stA(1, 1, t1);
    SBAR(); mmaq(0, 1); SBAR();
    // p3 (m1n1)
    ldA(0, 1);
    stB(0, 0, s0);
    SBAR(); mmaq(1, 1); SBAR();
    // p4 (m1n0): counted wait covers ALL of buf1/t1
    stB(0, 1, s0);
    WAITV(4);
    SBAR(); mmaq(1, 0); SBAR();
    // p5 (t odd, m0n0)
    ldA(1, 0); ldB(1, 0);
    stA(0, 0, s0);
    SBAR(); mmaq(0, 0); SBAR();
    // p6 (m0n1)
    ldB(1, 1);
    stA(0, 1, s0);
    SBAR(); mmaq(0, 1); SBAR();
    // p7 (m1n1)
    ldA(1, 1);
    stB(1, 0, s1);
    SBAR(); mmaq(1, 1); SBAR();
    // p8 (m1n0): counted wait covers ALL of buf0/t+2
    stB(1, 1, s1);
    WAITV(4);
    SBAR(); mmaq(1, 0); SBAR();
  }
  // tail: tiles 2NI-2, 2NI-1; stage only A1; drain at p4
  {
    const int t1 = 2 * NI - 1;
    ldA(0, 0); ldB(0, 0);
    stA(1, 0, t1);
    SBAR(); mmaq(0, 0); SBAR();
    ldB(0, 1);
    stA(1, 1, t1);
    SBAR(); mmaq(0, 1); SBAR();
    ldA(0, 1);
    SBAR(); mmaq(1, 1); SBAR();
    WAITV(0);
    SBAR(); mmaq(1, 0); SBAR();
    ldA(1, 0); ldB(1, 0);
    SBAR(); mmaq(0, 0); SBAR();
    ldB(1, 1);
    SBAR(); mmaq(0, 1); SBAR();
    ldA(1, 1);
    SBAR(); mmaq(1, 1); SBAR();
    mmaq(1, 0);
  }

  // epilogue
#pragma unroll
  for (int mi = 0; mi < 8; ++mi) {
    const int m = m0 + wm * 128 + mi * 16 + m16;
    const long rb = (long)m * N;
#pragma unroll
    for (int ni = 0; ni < 4; ++ni) {
      const int nb = n0 + wn * 64 + ni * 16 + quad * 4;
      f32x4 v = acc[mi][ni];
      const f32x4 bi = *(const f32x4*)(bias + nb);
#pragma unroll
      for (int r = 0; r < 4; r++) v[r] += bi[r];
      if (EPI & EPI_RESF) {
        const f32x4 rf = *(const f32x4*)(residF + rb + nb);
#pragma unroll
        for (int r = 0; r < 4; r++) v[r] += rf[r];
      }
      if (EPI & EPI_RESB) {
        const unsigned long long rv = *(const unsigned long long*)(residB + rb + nb);
#pragma unroll
        for (int r = 0; r < 4; r++) v[r] += bf2f((unsigned short)(rv >> (16 * r)));
      }
      if (EPI & EPI_GELU) {
#pragma unroll
        for (int r = 0; r < 4; r++) v[r] = gelu_f(v[r]);
      }
      if (EPI & EPI_OUTF) *(f32x4*)(outF + rb + nb) = v;
      if (EPI & EPI_OUTB) {
        unsigned long long o = 0;
#pragma unroll
        for (int r = 0; r < 4; r++) o |= (unsigned long long)f2bf(v[r]) << (16 * r);
        *(unsigned long long*)(outB + rb + nb) = o;
      }
    }
  }
}

// ---------------- Fastformer attention / pooling: MFMA Gram-matrix version ----------------
template<bool POOL>
__global__ __launch_bounds__(256) void fastattn2_k(
    const unsigned short* __restrict__ Q,
    const unsigned short* __restrict__ Kx,
    const unsigned short* __restrict__ V,
    int ld,
    const int* __restrict__ mask,
    unsigned short* __restrict__ attnO,
    unsigned short* __restrict__ fused,
    float* __restrict__ qres)
{
  const int lane = threadIdx.x & 63;
  const int wid  = threadIdx.x >> 6;
  const int gw   = blockIdx.x * 4 + wid;
  const int b = gw >> 3, h = gw & 7;
  const int c = lane & 15, quad = lane >> 4;
  const unsigned short* Qp = Q  + (long)b * 64 * ld + h * 96;
  const unsigned short* Kp = Kx + (long)b * 64 * ld + h * 96;
  const unsigned short* Vp = V  + (long)b * 64 * ld + h * 96;
  const float mval = (mask[b * 64 + lane] != 0) ? 1.0f : 0.0f;

  f32x4 G[4][4];
  f32x4 zero = {0.f, 0.f, 0.f, 0.f};
#pragma unroll
  for (int mi = 0; mi < 4; mi++)
#pragma unroll
    for (int ni = 0; ni < 4; ni++) G[mi][ni] = zero;
  float ql[4] = {0.f, 0.f, 0.f, 0.f};

#pragma unroll
  for (int kc = 0; kc < 3; kc++) {
    const int dcol = kc * 32 + quad * 8;
    short8 afr[4], bfr[4];
#pragma unroll
    for (int mi = 0; mi < 4; mi++)
      afr[mi] = *(const short8*)(Kp + (long)(mi * 16 + c) * ld + dcol);
#pragma unroll
    for (int ni = 0; ni < 4; ni++)
      bfr[ni] = *(const short8*)(Qp + (long)(ni * 16 + c) * ld + dcol);
#pragma unroll
    for (int ni = 0; ni < 4; ni++) {
      float t = 0.f;
#pragma unroll
      for (int j = 0; j < 8; j++) t += bf2f((unsigned short)bfr[ni][j]);
      ql[ni] += t;
    }
#pragma unroll
    for (int mi = 0; mi < 4; mi++)
#pragma unroll
      for (int ni = 0; ni < 4; ni++)
        G[mi][ni] = __builtin_amdgcn_mfma_f32_16x16x32_bf16(afr[mi], bfr[ni], G[mi][ni], 0, 0, 0);
  }
#pragma unroll
  for (int ni = 0; ni < 4; ni++) {
    ql[ni] += __shfl_xor(ql[ni], 16);
    ql[ni] += __shfl_xor(ql[ni], 32);
  }

  float qw[4];
  {
    float lg[4], mx = -3.4e38f;
#pragma unroll
    for (int ni = 0; ni < 4; ni++) {
      const float mk = __shfl(mval, ni * 16 + c);
      lg[ni] = (mk > 0.5f) ? ql[ni] * 0.102062072615966f : -10000.0f;
      mx = fmaxf(mx, lg[ni]);
    }
#pragma unroll
    for (int o = 1; o <= 8; o <<= 1) mx = fmaxf(mx, __shfl_xor(mx, o));
    float se = 0.f;
#pragma unroll
    for (int ni = 0; ni < 4; ni++) { qw[ni] = expf(lg[ni] - mx); se += qw[ni]; }
#pragma unroll
    for (int o = 1; o <= 8; o <<= 1) se += __shfl_xor(se, o);
    const float inv = 1.0f / se;
#pragma unroll
    for (int ni = 0; ni < 4; ni++) qw[ni] *= inv;
  }

  float kw[16];
#pragma unroll
  for (int mi = 0; mi < 4; mi++)
#pragma unroll
    for (int r = 0; r < 4; r++) {
      float a = 0.f;
#pragma unroll
      for (int ni = 0; ni < 4; ni++) a += G[mi][ni][r] * qw[ni];
      kw[mi * 4 + r] = a;
    }
#pragma unroll
  for (int i = 0; i < 16; i++)
#pragma unroll
    for (int o = 1; o <= 8; o <<= 1) kw[i] += __shfl_xor(kw[i], o);

  {
    float mx2 = -3.4e38f;
#pragma unroll
    for (int i = 0; i < 16; i++) {
      const int mi = i >> 2, r = i & 3;
      const float mk = __shfl(mval, mi * 16 + quad * 4 + r);
      kw[i] = (mk > 0.5f) ? kw[i] : -10000.0f;
      mx2 = fmaxf(mx2, kw[i]);
    }
    mx2 = fmaxf(mx2, __shfl_xor(mx2, 16));
    mx2 = fmaxf(mx2, __shfl_xor(mx2, 32));
    float se2 = 0.f;
#pragma unroll
    for (int i = 0; i < 16; i++) { kw[i] = expf(kw[i] - mx2); se2 += kw[i]; }
    se2 += __shfl_xor(se2, 16);
    se2 += __shfl_xor(se2, 32);
    const float inv = 1.0f / se2;
#pragma unroll
    for (int i = 0; i < 16; i++) kw[i] *= inv;
  }

  float vw[4];
  {
    float vl[4] = {0.f, 0.f, 0.f, 0.f};
#pragma unroll
    for (int ni = 0; ni < 4; ni++) {
#pragma unroll
      for (int mi = 0; mi < 4; mi++)
#pragma unroll
        for (int r = 0; r < 4; r++) vl[ni] += G[mi][ni][r] * kw[mi * 4 + r];
      vl[ni] += __shfl_xor(vl[ni], 16);
      vl[ni] += __shfl_xor(vl[ni], 32);
    }
    float mx = -3.4e38f;
#pragma unroll
    for (int ni = 0; ni < 4; ni++) {
      const float mk = __shfl(mval, ni * 16 + c);
      vl[ni] = (mk > 0.5f) ? vl[ni] : -10000.0f;
      mx = fmaxf(mx, vl[ni]);
    }
#pragma unroll
    for (int o = 1; o <= 8; o <<= 1) mx = fmaxf(mx, __shfl_xor(mx, o));
    float se = 0.f;
#pragma unroll
    for (int ni = 0; ni < 4; ni++) { vw[ni] = expf(vl[ni] - mx); se += vw[ni]; }
#pragma unroll
    for (int o = 1; o <= 8; o <<= 1) se += __shfl_xor(se, o);
    const float inv = 1.0f / se;
#pragma unroll
    for (int ni = 0; ni < 4; ni++) vw[ni] *= inv;
  }

  if (!POOL) {
    __shared__ float swv[4][64];
    if (quad == 0) {
#pragma unroll
      for (int ni = 0; ni < 4; ni++) swv[wid][ni * 16 + c] = vw[ni];
    }
    __syncthreads();
    unsigned short* Op = attnO + (long)b * 64 * 768 + h * 96;
#pragma unroll
    for (int it = 0; it < 12; it++) {
      const int idx = it * 64 + lane;
      const int s = idx / 12, cw = idx % 12;
      short8 v = *(const short8*)(Vp + (long)s * ld + cw * 8);
      const float w = swv[wid][s];
      short8 o;
#pragma unroll
      for (int j = 0; j < 8; j++) o[j] = (short)f2bf(w * bf2f((unsigned short)v[j]));
      *(short8*)(Op + (long)s * 768 + cw * 8) = o;
    }
  } else {
    float qg[24], vg[24];
#pragma unroll
    for (int kc = 0; kc < 3; kc++) {
      const int dcol = kc * 32 + quad * 8;
      short8 fq[4], fv[4];
#pragma unroll
      for (int ni = 0; ni < 4; ni++) {
        fq[ni] = *(const short8*)(Qp + (long)(ni * 16 + c) * ld + dcol);
        fv[ni] = *(const short8*)(Vp + (long)(ni * 16 + c) * ld + dcol);
      }
#pragma unroll
      for (int j = 0; j < 8; j++) {
        float aq = 0.f, av = 0.f;
#pragma unroll
        for (int ni = 0; ni < 4; ni++) {
          aq += qw[ni] * bf2f((unsigned short)fq[ni][j]);
          av += vw[ni] * bf2f((unsigned short)fv[ni][j]);
        }
        qg[kc * 8 + j] = aq; vg[kc * 8 + j] = av;
      }
    }
#pragma unroll
    for (int i = 0; i < 24; i++) {
#pragma unroll
      for (int o = 1; o <= 8; o <<= 1) {
        qg[i] += __shfl_xor(qg[i], o);
        vg[i] += __shfl_xor(vg[i], o);
      }
    }
    if (c == 0) {
#pragma unroll
      for (int kc = 0; kc < 3; kc++)
#pragma unroll
        for (int j = 0; j < 8; j++) {
          const int d = kc * 32 + quad * 8 + j;
          const float qv = qg[kc * 8 + j], vv = vg[kc * 8 + j];
          fused[(long)b * 1536 + d * 8 + h]        = f2bf(qv);
          fused[(long)b * 1536 + (96 + d) * 8 + h] = f2bf(vv);
          qres[(long)b * 768 + d * 8 + h] = qv;
        }
    }
  }
}

// ---------------- LayerNorms ----------------
__global__ __launch_bounds__(256) void ln768_k(
    const float* __restrict__ x, const float* __restrict__ g, const float* __restrict__ b,
    unsigned short* __restrict__ out)
{
  const int tid = threadIdx.x;
  const long row = blockIdx.x;
  const float* xr = x + row * 768;
  const float v0 = xr[tid], v1 = xr[tid + 256], v2 = xr[tid + 512];
  __shared__ float red[4];
  const int wid = tid >> 6, ln = tid & 63;
  float s = wsum(v0 + v1 + v2);
  if (ln == 0) red[wid] = s;
  __syncthreads();
  const float mean = (red[0] + red[1] + red[2] + red[3]) * (1.0f / 768.0f);
  __syncthreads();
  const float d0 = v0 - mean, d1 = v1 - mean, d2 = v2 - mean;
  float q = wsum(d0 * d0 + d1 * d1 + d2 * d2);
  if (ln == 0) red[wid] = q;
  __syncthreads();
  const float var = (red[0] + red[1] + red[2] + red[3]) * (1.0f / 768.0f);
  const float rs = rsqrtf(var + 1e-5f);
  unsigned short* o = out + row * 768;
  o[tid]       = f2bf(d0 * rs * g[tid]       + b[tid]);
  o[tid + 256] = f2bf(d1 * rs * g[tid + 256] + b[tid + 256]);
  o[tid + 512] = f2bf(d2 * rs * g[tid + 512] + b[tid + 512]);
}

__global__ __launch_bounds__(256) void ln768b_k(
    const unsigned short* __restrict__ x, const float* __restrict__ g, const float* __restrict__ b,
    unsigned short* __restrict__ out)
{
  const int tid = threadIdx.x;
  const long row = blockIdx.x;
  const unsigned short* xr = x + row * 768;
  const float v0 = bf2f(xr[tid]), v1 = bf2f(xr[tid + 256]), v2 = bf2f(xr[tid + 512]);
  __shared__ float red[4];
  const int wid = tid >> 6, ln = tid & 63;
  float s = wsum(v0 + v1 + v2);
  if (ln == 0) red[wid] = s;
  __syncthreads();
  const float mean = (red[0] + red[1] + red[2] + red[3]) * (1.0f / 768.0f);
  __syncthreads();
  const float d0 = v0 - mean, d1 = v1 - mean, d2 = v2 - mean;
  float q = wsum(d0 * d0 + d1 * d1 + d2 * d2);
  if (ln == 0) red[wid] = q;
  __syncthreads();
  const float var = (red[0] + red[1] + red[2] + red[3]) * (1.0f / 768.0f);
  const float rs = rsqrtf(var + 1e-5f);
  unsigned short* o = out + row * 768;
  o[tid]       = f2bf(d0 * rs * g[tid]       + b[tid]);
  o[tid + 256] = f2bf(d1 * rs * g[tid + 256] + b[tid + 256]);
  o[tid + 512] = f2bf(d2 * rs * g[tid + 512] + b[tid + 512]);
}

__global__ __launch_bounds__(256) void ln2x_k(
    const float* __restrict__ x,
    const float* __restrict__ g1, const float* __restrict__ b1,
    const float* __restrict__ g2, const float* __restrict__ b2,
    unsigned short* __restrict__ out)
{
  const int tid = threadIdx.x;
  const long row = blockIdx.x;
  const float* xr = x + row * 768;
  const float v0 = xr[tid], v1 = xr[tid + 256], v2 = xr[tid + 512];
  __shared__ float red[4];
  const int wid = tid >> 6, ln = tid & 63;
  float s = wsum(v0 + v1 + v2);
  if (ln == 0) red[wid] = s;
  __syncthreads();
  const float mean = (red[0] + red[1] + red[2] + red[3]) * (1.0f / 768.0f);
  __syncthreads();
  const float d0 = v0 - mean, d1 = v1 - mean, d2 = v2 - mean;
  float q = wsum(d0 * d0 + d1 * d1 + d2 * d2);
  if (ln == 0) red[wid] = q;
  __syncthreads();
  const float var = (red[0] + red[1] + red[2] + red[3]) * (1.0f / 768.0f);
  const float rs = rsqrtf(var + 1e-5f);
  const float y0 = d0 * rs * g1[tid]       + b1[tid];
  const float y1 = d1 * rs * g1[tid + 256] + b1[tid + 256];
  const float y2 = d2 * rs * g1[tid + 512] + b1[tid + 512];
  __syncthreads();
  float s2 = wsum(y0 + y1 + y2);
  if (ln == 0) red[wid] = s2;
  __syncthreads();
  const float mean2 = (red[0] + red[1] + red[2] + red[3]) * (1.0f / 768.0f);
  __syncthreads();
  const float e0 = y0 - mean2, e1 = y1 - mean2, e2 = y2 - mean2;
  float q2 = wsum(e0 * e0 + e1 * e1 + e2 * e2);
  if (ln == 0) red[wid] = q2;
  __syncthreads();
  const float var2 = (red[0] + red[1] + red[2] + red[3]) * (1.0f / 768.0f);
  const float rs2 = rsqrtf(var2 + 1e-5f);
  unsigned short* o = out + row * 768;
  o[tid]       = f2bf(e0 * rs2 * g2[tid]       + b2[tid]);
  o[tid + 256] = f2bf(e1 * rs2 * g2[tid + 256] + b2[tid + 256]);
  o[tid + 512] = f2bf(e2 * rs2 * g2[tid + 512] + b2[tid + 512]);
}

__global__ __launch_bounds__(256) void lnf_k(
    const float* __restrict__ x, const float* __restrict__ g, const float* __restrict__ b,
    float* __restrict__ out)
{
  const int tid = threadIdx.x;
  const long row = blockIdx.x;
  const float v = x[row * 256 + tid];
  __shared__ float red[4];
  const int wid = tid >> 6, ln = tid & 63;
  float s = wsum(v);
  if (ln == 0) red[wid] = s;
  __syncthreads();
  const float mean = (red[0] + red[1] + red[2] + red[3]) * (1.0f / 256.0f);
  __syncthreads();
  const float d = v - mean;
  float q = wsum(d * d);
  if (ln == 0) red[wid] = q;
  __syncthreads();
  const float var = (red[0] + red[1] + red[2] + red[3]) * (1.0f / 256.0f);
  const float rs = rsqrtf(var + 1e-5f);
  out[row * 256 + tid] = d * rs * g[tid] + b[tid];
}

// ---------------- weight transpose + cast, bias concat ----------------
__global__ __launch_bounds__(256) void tcast_k(
    const float* __restrict__ W, unsigned short* __restrict__ Wt, int K, int N)
{
  __shared__ float t[32][33];
  const int tx = threadIdx.x & 31, ty = threadIdx.x >> 5;
  const int n0 = blockIdx.x * 32, k0 = blockIdx.y * 32;
#pragma unroll
  for (int j = 0; j < 32; j += 8)
    t[ty + j][tx] = W[(long)(k0 + ty + j) * N + n0 + tx];
  __syncthreads();
#pragma unroll
  for (int j = 0; j < 32; j += 8)
    Wt[(long)(n0 + ty + j) * K + k0 + tx] = f2bf(t[tx][ty + j]);
}

__global__ __launch_bounds__(256) void cat3_k(
    const float* __restrict__ a, const float* __restrict__ b, const float* __restrict__ c,
    float* __restrict__ dst)
{
  const int i = blockIdx.x * 256 + threadIdx.x;   // grid 9 -> 2304
  dst[i] = (i < 768) ? a[i] : (i < 1536 ? b[i - 768] : c[i - 1536]);
}

// ---------------- launcher ----------------
extern "C" void kernel_launch(void* const* d_in, const int* in_sizes, int n_in,
                              void* d_out, int out_size, void* d_ws, size_t ws_size,
                              hipStream_t stream)
{
  const float* x    = (const float*)d_in[0];
  const int*   mask = (const int*)d_in[1];
  const float* n1g = (const float*)d_in[2];  const float* n1b = (const float*)d_in[3];
  const float* wq  = (const float*)d_in[4];  const float* bq  = (const float*)d_in[5];
  const float* wk  = (const float*)d_in[6];  const float* bk  = (const float*)d_in[7];
  const float* wv  = (const float*)d_in[8];  const float* bv  = (const float*)d_in[9];
  const float* wo  = (const float*)d_in[10]; const float* bo  = (const float*)d_in[11];
  const float* n2g = (const float*)d_in[12]; const float* n2b = (const float*)d_in[13];
  const float* w1  = (const float*)d_in[14]; const float* b1  = (const float*)d_in[15];
  const float* w2  = (const float*)d_in[16]; const float* b2  = (const float*)d_in[17];
  const float* pwq = (const float*)d_in[18]; const float* pbq = (const float*)d_in[19];
  const float* pwk = (const float*)d_in[20]; const float* pbk = (const float*)d_in[21];
  const float* pwv = (const float*)d_in[22]; const float* pbv = (const float*)d_in[23];
  const float* pwo = (const float*)d_in[24]; const float* pbo = (const float*)d_in[25];
  const float* png = (const float*)d_in[26]; const float* pnb = (const float*)d_in[27];
  const float* tng = (const float*)d_in[28]; const float* tnb = (const float*)d_in[29];
  const float* pjw = (const float*)d_in[30]; const float* pjb = (const float*)d_in[31];
  const float* ong = (const float*)d_in[32]; const float* onb = (const float*)d_in[33];
  float* out = (float*)d_out;

  // 128 KiB dynamic LDS opt-in for the one 8-phase instantiation
  static int lds_attr_done = 0;
  if (!lds_attr_done) {
    lds_attr_done = 1;
    hipFuncSetAttribute((const void*)gemm256_k<EPI_OUTB>,
                        hipFuncAttributeMaxDynamicSharedMemorySize, 131072);
  }

  char* p = (char*)d_ws;
  auto alloc = [&](size_t n) { void* r = (void*)p; p += (n + 255) & ~(size_t)255; return r; };

  unsigned short* wqkvt = (unsigned short*)alloc((size_t)3 * HID * HID * 2);  // 2304 x 768
  unsigned short* wot   = (unsigned short*)alloc((size_t)HID * HID * 2);
  unsigned short* w1t   = (unsigned short*)alloc((size_t)FFND * HID * 2);
  unsigned short* w2t   = (unsigned short*)alloc((size_t)HID * FFND * 2);
  unsigned short* pqkvt = (unsigned short*)alloc((size_t)3 * HID * HID * 2);
  unsigned short* pwot  = (unsigned short*)alloc((size_t)HID * 2 * HID * 2);
  unsigned short* pjwt  = (unsigned short*)alloc((size_t)EOUTD * HID * 2);
  float*          qkvbias = (float*)alloc((size_t)3 * HID * 4);
  float*          pqkvbias= (float*)alloc((size_t)3 * HID * 4);
  unsigned short* bfA   = (unsigned short*)alloc((size_t)TOK * HID * 2);      // h1 -> h -> x3
  unsigned short* QKVb  = (unsigned short*)alloc((size_t)TOK * 3 * HID * 2);  // 65536 x 2304; FFN hidden alias
  unsigned short* bfB   = (unsigned short*)alloc((size_t)TOK * HID * 2);      // attn out
  unsigned short* x2b   = (unsigned short*)alloc((size_t)TOK * HID * 2);      // x2 (bf16)
  unsigned short* fusedb= (unsigned short*)alloc((size_t)BATCH * 2 * HID * 2);
  float*          qresb = (float*)alloc((size_t)BATCH * HID * 4);
  float*          preln = (float*)alloc((size_t)BATCH * HID * 4);
  unsigned short* pooledb=(unsigned short*)alloc((size_t)BATCH * HID * 2);
  float*          news  = (float*)alloc((size_t)BATCH * EOUTD * 4);
  (void)ws_size; (void)in_sizes; (void)n_in; (void)out_size;

  // weight prep
  tcast_k<<<dim3(HID/32,  HID/32),  256, 0, stream>>>(wq,  wqkvt,                 HID, HID);
  tcast_k<<<dim3(HID/32,  HID/32),  256, 0, stream>>>(wk,  wqkvt + (size_t)HID*HID,   HID, HID);
  tcast_k<<<dim3(HID/32,  HID/32),  256, 0, stream>>>(wv,  wqkvt + (size_t)2*HID*HID, HID, HID);
  tcast_k<<<dim3(HID/32,  HID/32),  256, 0, stream>>>(wo,  wot,  HID,  HID);
  tcast_k<<<dim3(FFND/32, HID/32),  256, 0, stream>>>(w1,  w1t,  HID,  FFND);
  tcast_k<<<dim3(HID/32,  FFND/32), 256, 0, stream>>>(w2,  w2t,  FFND, HID);
  tcast_k<<<dim3(HID/32,  HID/32),  256, 0, stream>>>(pwq, pqkvt,                 HID, HID);
  tcast_k<<<dim3(HID/32,  HID/32),  256, 0, stream>>>(pwk, pqkvt + (size_t)HID*HID,   HID, HID);
  tcast_k<<<dim3(HID/32,  HID/32),  256, 0, stream>>>(pwv, pqkvt + (size_t)2*HID*HID, HID, HID);
  tcast_k<<<dim3(HID/32,  (2*HID)/32), 256, 0, stream>>>(pwo, pwot, 2*HID, HID);
  tcast_k<<<dim3(EOUTD/32, HID/32), 256, 0, stream>>>(pjw, pjwt, HID,  EOUTD);
  cat3_k<<<9, 256, 0, stream>>>(bq,  bk,  bv,  qkvbias);
  cat3_k<<<9, 256, 0, stream>>>(pbq, pbk, pbv, pqkvbias);

  // LN1
  ln768_k<<<TOK, 256, 0, stream>>>(x, n1g, n1b, bfA);

  // fused QKV GEMM (A/B arm 1: 8-phase asm-opaque 256^2)
  gemm256_k<EPI_OUTB><<<(TOK/256)*(3*HID/256), 512, 131072, stream>>>(
      bfA, wqkvt, qkvbias, nullptr, nullptr, nullptr, QKVb, TOK, 3*HID, HID);

  // fastformer attention -> bfB (stride 768)
  fastattn2_k<false><<<BATCH * NHEAD / 4, 256, 0, stream>>>(
      QKVb, QKVb + HID, QKVb + 2*HID, 3*HID, mask, bfB, nullptr, nullptr);

  // wo proj + f32 resid x -> x2 (bf16)   [128^2]
  gemm_k<EPI_OUTB | EPI_RESF><<<(TOK/128)*(HID/128), 256, 0, stream>>>(
      bfB, wot, bo, x, nullptr, nullptr, x2b, TOK, HID, HID);

  // LN2 (bf16 in)
  ln768b_k<<<TOK, 256, 0, stream>>>(x2b, n2g, n2b, bfA);

  // FFN in 2 row-chunks of 32768; hidden lives in QKVb (dead until pool QKV)  [128^2]
  for (int c = 0; c < 2; c++) {
    const size_t ro = (size_t)c * 32768;
    gemm_k<EPI_OUTB | EPI_GELU><<<(32768/128)*(FFND/128), 256, 0, stream>>>(
        bfA + ro * HID, w1t, b1, nullptr, nullptr, nullptr, QKVb, 32768, FFND, HID);
    gemm_k<EPI_OUTB | EPI_RESB><<<(32768/128)*(HID/128), 256, 0, stream>>>(
        QKVb, w2t, b2, nullptr, x2b + ro * HID, nullptr, bfA + ro * HID, 32768, HID, FFND);
  }
  // bfA = x3 (bf16)

  // fused pool QKV GEMM (A/B arm 2: identical shape, proven 128^2 kernel)
  gemm_k<EPI_OUTB><<<(TOK/128)*(3*HID/128), 256, 0, stream>>>(
      bfA, pqkvt, pqkvbias, nullptr, nullptr, nullptr, QKVb, TOK, 3*HID, HID);

  // pooling core
  fastattn2_k<true><<<BATCH * NHEAD / 4, 256, 0, stream>>>(
      QKVb, QKVb + HID, QKVb + 2*HID, 3*HID, mask, nullptr, fusedb, qresb);

  // pool out proj (+qres) -> preln f32  [128^2]
  gemm_k<EPI_OUTF | EPI_RESF><<<(BATCH/128)*(HID/128), 256, 0, stream>>>(
      fusedb, pwot, pbo, qresb, nullptr, preln, nullptr, BATCH, HID, 2*HID);

  // double LN -> pooled bf16
  ln2x_k<<<BATCH, 256, 0, stream>>>(preln, png, pnb, tng, tnb, pooledb);

  // proj -> news f32  [128^2]
  gemm_k<EPI_OUTF><<<(BATCH/128)*(EOUTD/128), 256, 0, stream>>>(
      pooledb, pjwt, pjb, nullptr, nullptr, news, nullptr, BATCH, EOUTD, HID);

  // final LN
  lnf_k<<<BATCH, 256, 0, stream>>>(news, ong, onb, out);
}

// Round 13
// 2138.915 us; speedup vs baseline: 1.2559x; 1.2559x over previous
//
#include <hip/hip_runtime.h>
#include <math.h>

// ---------------- configuration ----------------
#define NHEAD 8
#define HID   768
#define FFND  3072
#define EOUTD 256
#define BATCH 1024
#define TOK   (BATCH*64)   // 65536

#define EPI_RESF  1
#define EPI_RESB  2
#define EPI_GELU  4
#define EPI_OUTF  8
#define EPI_OUTB  16

typedef __attribute__((ext_vector_type(8))) short short8;   // 8 x bf16
typedef __attribute__((ext_vector_type(4))) float f32x4;    // MFMA C/D

#define AS1 __attribute__((address_space(1)))
#define AS3 __attribute__((address_space(3)))

__device__ __forceinline__ void async16(const void* g, void* l) {
  __builtin_amdgcn_global_load_lds(
      (AS1 unsigned int*)(unsigned long long)g,
      (AS3 unsigned int*)(unsigned int)(unsigned long long)l,
      16, 0, 0);
}

__device__ __forceinline__ float bf2f(unsigned short u) {
  union { unsigned int i; float f; } c; c.i = ((unsigned int)u) << 16; return c.f;
}
__device__ __forceinline__ unsigned short f2bf(float f) {
  union { float f; unsigned int i; } c; c.f = f;
  unsigned int x = c.i + 0x7fffu + ((c.i >> 16) & 1u);   // RNE
  return (unsigned short)(x >> 16);
}
__device__ __forceinline__ float wsum(float v) {
#pragma unroll
  for (int o = 32; o > 0; o >>= 1) v += __shfl_xor(v, o);
  return v;
}
// GELU with fast erf (Abramowitz-Stegun 7.1.26, |err| < 1.5e-7)
__device__ __forceinline__ float gelu_f(float v) {
  const float z = fabsf(v) * 0.70710678118654752f;
  const float t = 1.0f / (1.0f + 0.3275911f * z);
  const float poly = t * (0.254829592f + t * (-0.284496736f +
                     t * (1.421413741f + t * (-1.453152027f + t * 1.061405429f))));
  float erfv = 1.0f - poly * __expf(-z * z);
  erfv = (v < 0.f) ? -erfv : erfv;
  return 0.5f * v * (1.0f + erfv);
}

// ---------------- GEMM 128x128 (proven workhorse; ~800 TF, m97-structure) ----------------
// HISTORY (do not regress): 256^2 8-phase attempts both LOST on HW:
//  R4 (memory-clobber fences): waitcnt pass inserted vmcnt(0) drains at every
//     barrier while LDS-DMA outstanding -> 358us @ 27.8% MfmaUtil.
//  R12 (volatile-asm ds_reads + sched_barrier(0) pinning): scheduler/allocator
//     defeated -> scratch spills (FETCH 266->641MB, WRITE 433->581MB) ->
//     752us @ 12.6% MfmaUtil. Guide m141 failure mode.
// The 128^2 2-barrier kernel at 290us/36% MfmaUtil is the verified optimum
// for this toolchain at these shapes.
template<int EPI>
__global__ __launch_bounds__(256, 3) void gemm_k(
    const unsigned short* __restrict__ A, const unsigned short* __restrict__ Wt,
    const float* __restrict__ bias,
    const float* __restrict__ residF, const unsigned short* __restrict__ residB,
    float* __restrict__ outF, unsigned short* __restrict__ outB,
    int M, int N, int K)
{
  __shared__ unsigned short lA[128 * 64];
  __shared__ unsigned short lB[128 * 64];
  const int tid  = threadIdx.x;

  const int nT  = N >> 7;
  const int per = gridDim.x >> 3;
  const int tile = (blockIdx.x & 7) * per + (blockIdx.x >> 3);
  int m_idx = tile / nT;
  int n_idx = tile - m_idx * nT;
  if (m_idx & 1) n_idx = nT - 1 - n_idx;
  const int n0 = n_idx * 128;
  const int m0 = m_idx * 128;

  const int lane = tid & 63;
  const int wid  = tid >> 6;
  const int wm   = wid & 1, wn = wid >> 1;
  const int m16  = lane & 15, quad = lane >> 4;

  f32x4 zero = {0.0f, 0.0f, 0.0f, 0.0f};
  f32x4 acc[4][4];
#pragma unroll
  for (int i = 0; i < 4; i++)
#pragma unroll
    for (int j = 0; j < 4; j++) acc[i][j] = zero;

  long aoff[4], boff[4];
#pragma unroll
  for (int j = 0; j < 4; j++) {
    const int L = tid + j * 256;
    const int row = L >> 3;
    const int kc  = (L & 7) ^ (row & 7);
    aoff[j] = (long)(m0 + row) * K + kc * 8;
    boff[j] = (long)(n0 + row) * K + kc * 8;
  }

  for (int k0 = 0; k0 < K; k0 += 64) {
#pragma unroll
    for (int j = 0; j < 4; j++)
      async16(A + aoff[j] + k0, lA + (size_t)(j * 256 + wid * 64) * 8);
#pragma unroll
    for (int j = 0; j < 4; j++)
      async16(Wt + boff[j] + k0, lB + (size_t)(j * 256 + wid * 64) * 8);
    __syncthreads();
#pragma unroll
    for (int s = 0; s < 2; s++) {
      short8 af[4], bfr[4];
#pragma unroll
      for (int mi = 0; mi < 4; mi++) {
        const int row = wm * 64 + mi * 16 + m16;
        const int kc  = (s * 4 + quad) ^ (row & 7);
        af[mi] = *(const short8*)(lA + row * 64 + kc * 8);
      }
#pragma unroll
      for (int ni = 0; ni < 4; ni++) {
        const int row = wn * 64 + ni * 16 + m16;
        const int kc  = (s * 4 + quad) ^ (row & 7);
        bfr[ni] = *(const short8*)(lB + row * 64 + kc * 8);
      }
#pragma unroll
      for (int mi = 0; mi < 4; mi++)
#pragma unroll
        for (int ni = 0; ni < 4; ni++)
          acc[mi][ni] = __builtin_amdgcn_mfma_f32_16x16x32_bf16(bfr[ni], af[mi], acc[mi][ni], 0, 0, 0);
    }
    __syncthreads();
  }

#pragma unroll
  for (int mi = 0; mi < 4; mi++) {
    const int m = m0 + wm * 64 + mi * 16 + m16;
    const long rb = (long)m * N;
#pragma unroll
    for (int ni = 0; ni < 4; ni++) {
      const int nb = n0 + wn * 64 + ni * 16 + quad * 4;
      f32x4 v = acc[mi][ni];
      const f32x4 bi = *(const f32x4*)(bias + nb);
#pragma unroll
      for (int r = 0; r < 4; r++) v[r] += bi[r];
      if (EPI & EPI_RESF) {
        const f32x4 rf = *(const f32x4*)(residF + rb + nb);
#pragma unroll
        for (int r = 0; r < 4; r++) v[r] += rf[r];
      }
      if (EPI & EPI_RESB) {
        const unsigned long long rv = *(const unsigned long long*)(residB + rb + nb);
#pragma unroll
        for (int r = 0; r < 4; r++) v[r] += bf2f((unsigned short)(rv >> (16 * r)));
      }
      if (EPI & EPI_GELU) {
#pragma unroll
        for (int r = 0; r < 4; r++) v[r] = gelu_f(v[r]);
      }
      if (EPI & EPI_OUTF) *(f32x4*)(outF + rb + nb) = v;
      if (EPI & EPI_OUTB) {
        unsigned long long o = 0;
#pragma unroll
        for (int r = 0; r < 4; r++) o |= (unsigned long long)f2bf(v[r]) << (16 * r);
        *(unsigned long long*)(outB + rb + nb) = o;
      }
    }
  }
}

// ---------------- Fastformer attention / pooling: MFMA Gram-matrix version ----------------
template<bool POOL>
__global__ __launch_bounds__(256) void fastattn2_k(
    const unsigned short* __restrict__ Q,
    const unsigned short* __restrict__ Kx,
    const unsigned short* __restrict__ V,
    int ld,
    const int* __restrict__ mask,
    unsigned short* __restrict__ attnO,
    unsigned short* __restrict__ fused,
    float* __restrict__ qres)
{
  const int lane = threadIdx.x & 63;
  const int wid  = threadIdx.x >> 6;
  const int gw   = blockIdx.x * 4 + wid;
  const int b = gw >> 3, h = gw & 7;
  const int c = lane & 15, quad = lane >> 4;
  const unsigned short* Qp = Q  + (long)b * 64 * ld + h * 96;
  const unsigned short* Kp = Kx + (long)b * 64 * ld + h * 96;
  const unsigned short* Vp = V  + (long)b * 64 * ld + h * 96;
  const float mval = (mask[b * 64 + lane] != 0) ? 1.0f : 0.0f;

  f32x4 G[4][4];
  f32x4 zero = {0.f, 0.f, 0.f, 0.f};
#pragma unroll
  for (int mi = 0; mi < 4; mi++)
#pragma unroll
    for (int ni = 0; ni < 4; ni++) G[mi][ni] = zero;
  float ql[4] = {0.f, 0.f, 0.f, 0.f};

#pragma unroll
  for (int kc = 0; kc < 3; kc++) {
    const int dcol = kc * 32 + quad * 8;
    short8 afr[4], bfr[4];
#pragma unroll
    for (int mi = 0; mi < 4; mi++)
      afr[mi] = *(const short8*)(Kp + (long)(mi * 16 + c) * ld + dcol);
#pragma unroll
    for (int ni = 0; ni < 4; ni++)
      bfr[ni] = *(const short8*)(Qp + (long)(ni * 16 + c) * ld + dcol);
#pragma unroll
    for (int ni = 0; ni < 4; ni++) {
      float t = 0.f;
#pragma unroll
      for (int j = 0; j < 8; j++) t += bf2f((unsigned short)bfr[ni][j]);
      ql[ni] += t;
    }
#pragma unroll
    for (int mi = 0; mi < 4; mi++)
#pragma unroll
      for (int ni = 0; ni < 4; ni++)
        G[mi][ni] = __builtin_amdgcn_mfma_f32_16x16x32_bf16(afr[mi], bfr[ni], G[mi][ni], 0, 0, 0);
  }
#pragma unroll
  for (int ni = 0; ni < 4; ni++) {
    ql[ni] += __shfl_xor(ql[ni], 16);
    ql[ni] += __shfl_xor(ql[ni], 32);
  }

  float qw[4];
  {
    float lg[4], mx = -3.4e38f;
#pragma unroll
    for (int ni = 0; ni < 4; ni++) {
      const float mk = __shfl(mval, ni * 16 + c);
      lg[ni] = (mk > 0.5f) ? ql[ni] * 0.102062072615966f : -10000.0f;
      mx = fmaxf(mx, lg[ni]);
    }
#pragma unroll
    for (int o = 1; o <= 8; o <<= 1) mx = fmaxf(mx, __shfl_xor(mx, o));
    float se = 0.f;
#pragma unroll
    for (int ni = 0; ni < 4; ni++) { qw[ni] = expf(lg[ni] - mx); se += qw[ni]; }
#pragma unroll
    for (int o = 1; o <= 8; o <<= 1) se += __shfl_xor(se, o);
    const float inv = 1.0f / se;
#pragma unroll
    for (int ni = 0; ni < 4; ni++) qw[ni] *= inv;
  }

  float kw[16];
#pragma unroll
  for (int mi = 0; mi < 4; mi++)
#pragma unroll
    for (int r = 0; r < 4; r++) {
      float a = 0.f;
#pragma unroll
      for (int ni = 0; ni < 4; ni++) a += G[mi][ni][r] * qw[ni];
      kw[mi * 4 + r] = a;
    }
#pragma unroll
  for (int i = 0; i < 16; i++)
#pragma unroll
    for (int o = 1; o <= 8; o <<= 1) kw[i] += __shfl_xor(kw[i], o);

  {
    float mx2 = -3.4e38f;
#pragma unroll
    for (int i = 0; i < 16; i++) {
      const int mi = i >> 2, r = i & 3;
      const float mk = __shfl(mval, mi * 16 + quad * 4 + r);
      kw[i] = (mk > 0.5f) ? kw[i] : -10000.0f;
      mx2 = fmaxf(mx2, kw[i]);
    }
    mx2 = fmaxf(mx2, __shfl_xor(mx2, 16));
    mx2 = fmaxf(mx2, __shfl_xor(mx2, 32));
    float se2 = 0.f;
#pragma unroll
    for (int i = 0; i < 16; i++) { kw[i] = expf(kw[i] - mx2); se2 += kw[i]; }
    se2 += __shfl_xor(se2, 16);
    se2 += __shfl_xor(se2, 32);
    const float inv = 1.0f / se2;
#pragma unroll
    for (int i = 0; i < 16; i++) kw[i] *= inv;
  }

  float vw[4];
  {
    float vl[4] = {0.f, 0.f, 0.f, 0.f};
#pragma unroll
    for (int ni = 0; ni < 4; ni++) {
#pragma unroll
      for (int mi = 0; mi < 4; mi++)
#pragma unroll
        for (int r = 0; r < 4; r++) vl[ni] += G[mi][ni][r] * kw[mi * 4 + r];
      vl[ni] += __shfl_xor(vl[ni], 16);
      vl[ni] += __shfl_xor(vl[ni], 32);
    }
    float mx = -3.4e38f;
#pragma unroll
    for (int ni = 0; ni < 4; ni++) {
      const float mk = __shfl(mval, ni * 16 + c);
      vl[ni] = (mk > 0.5f) ? vl[ni] : -10000.0f;
      mx = fmaxf(mx, vl[ni]);
    }
#pragma unroll
    for (int o = 1; o <= 8; o <<= 1) mx = fmaxf(mx, __shfl_xor(mx, o));
    float se = 0.f;
#pragma unroll
    for (int ni = 0; ni < 4; ni++) { vw[ni] = expf(vl[ni] - mx); se += vw[ni]; }
#pragma unroll
    for (int o = 1; o <= 8; o <<= 1) se += __shfl_xor(se, o);
    const float inv = 1.0f / se;
#pragma unroll
    for (int ni = 0; ni < 4; ni++) vw[ni] *= inv;
  }

  if (!POOL) {
    __shared__ float swv[4][64];
    if (quad == 0) {
#pragma unroll
      for (int ni = 0; ni < 4; ni++) swv[wid][ni * 16 + c] = vw[ni];
    }
    __syncthreads();
    unsigned short* Op = attnO + (long)b * 64 * 768 + h * 96;
#pragma unroll
    for (int it = 0; it < 12; it++) {
      const int idx = it * 64 + lane;
      const int s = idx / 12, cw = idx % 12;
      short8 v = *(const short8*)(Vp + (long)s * ld + cw * 8);
      const float w = swv[wid][s];
      short8 o;
#pragma unroll
      for (int j = 0; j < 8; j++) o[j] = (short)f2bf(w * bf2f((unsigned short)v[j]));
      *(short8*)(Op + (long)s * 768 + cw * 8) = o;
    }
  } else {
    float qg[24], vg[24];
#pragma unroll
    for (int kc = 0; kc < 3; kc++) {
      const int dcol = kc * 32 + quad * 8;
      short8 fq[4], fv[4];
#pragma unroll
      for (int ni = 0; ni < 4; ni++) {
        fq[ni] = *(const short8*)(Qp + (long)(ni * 16 + c) * ld + dcol);
        fv[ni] = *(const short8*)(Vp + (long)(ni * 16 + c) * ld + dcol);
      }
#pragma unroll
      for (int j = 0; j < 8; j++) {
        float aq = 0.f, av = 0.f;
#pragma unroll
        for (int ni = 0; ni < 4; ni++) {
          aq += qw[ni] * bf2f((unsigned short)fq[ni][j]);
          av += vw[ni] * bf2f((unsigned short)fv[ni][j]);
        }
        qg[kc * 8 + j] = aq; vg[kc * 8 + j] = av;
      }
    }
#pragma unroll
    for (int i = 0; i < 24; i++) {
#pragma unroll
      for (int o = 1; o <= 8; o <<= 1) {
        qg[i] += __shfl_xor(qg[i], o);
        vg[i] += __shfl_xor(vg[i], o);
      }
    }
    if (c == 0) {
#pragma unroll
      for (int kc = 0; kc < 3; kc++)
#pragma unroll
        for (int j = 0; j < 8; j++) {
          const int d = kc * 32 + quad * 8 + j;
          const float qv = qg[kc * 8 + j], vv = vg[kc * 8 + j];
          fused[(long)b * 1536 + d * 8 + h]        = f2bf(qv);
          fused[(long)b * 1536 + (96 + d) * 8 + h] = f2bf(vv);
          qres[(long)b * 768 + d * 8 + h] = qv;
        }
    }
  }
}

// ---------------- LayerNorms ----------------
__global__ __launch_bounds__(256) void ln768_k(
    const float* __restrict__ x, const float* __restrict__ g, const float* __restrict__ b,
    unsigned short* __restrict__ out)
{
  const int tid = threadIdx.x;
  const long row = blockIdx.x;
  const float* xr = x + row * 768;
  const float v0 = xr[tid], v1 = xr[tid + 256], v2 = xr[tid + 512];
  __shared__ float red[4];
  const int wid = tid >> 6, ln = tid & 63;
  float s = wsum(v0 + v1 + v2);
  if (ln == 0) red[wid] = s;
  __syncthreads();
  const float mean = (red[0] + red[1] + red[2] + red[3]) * (1.0f / 768.0f);
  __syncthreads();
  const float d0 = v0 - mean, d1 = v1 - mean, d2 = v2 - mean;
  float q = wsum(d0 * d0 + d1 * d1 + d2 * d2);
  if (ln == 0) red[wid] = q;
  __syncthreads();
  const float var = (red[0] + red[1] + red[2] + red[3]) * (1.0f / 768.0f);
  const float rs = rsqrtf(var + 1e-5f);
  unsigned short* o = out + row * 768;
  o[tid]       = f2bf(d0 * rs * g[tid]       + b[tid]);
  o[tid + 256] = f2bf(d1 * rs * g[tid + 256] + b[tid + 256]);
  o[tid + 512] = f2bf(d2 * rs * g[tid + 512] + b[tid + 512]);
}

__global__ __launch_bounds__(256) void ln768b_k(
    const unsigned short* __restrict__ x, const float* __restrict__ g, const float* __restrict__ b,
    unsigned short* __restrict__ out)
{
  const int tid = threadIdx.x;
  const long row = blockIdx.x;
  const unsigned short* xr = x + row * 768;
  const float v0 = bf2f(xr[tid]), v1 = bf2f(xr[tid + 256]), v2 = bf2f(xr[tid + 512]);
  __shared__ float red[4];
  const int wid = tid >> 6, ln = tid & 63;
  float s = wsum(v0 + v1 + v2);
  if (ln == 0) red[wid] = s;
  __syncthreads();
  const float mean = (red[0] + red[1] + red[2] + red[3]) * (1.0f / 768.0f);
  __syncthreads();
  const float d0 = v0 - mean, d1 = v1 - mean, d2 = v2 - mean;
  float q = wsum(d0 * d0 + d1 * d1 + d2 * d2);
  if (ln == 0) red[wid] = q;
  __syncthreads();
  const float var = (red[0] + red[1] + red[2] + red[3]) * (1.0f / 768.0f);
  const float rs = rsqrtf(var + 1e-5f);
  unsigned short* o = out + row * 768;
  o[tid]       = f2bf(d0 * rs * g[tid]       + b[tid]);
  o[tid + 256] = f2bf(d1 * rs * g[tid + 256] + b[tid + 256]);
  o[tid + 512] = f2bf(d2 * rs * g[tid + 512] + b[tid + 512]);
}

__global__ __launch_bounds__(256) void ln2x_k(
    const float* __restrict__ x,
    const float* __restrict__ g1, const float* __restrict__ b1,
    const float* __restrict__ g2, const float* __restrict__ b2,
    unsigned short* __restrict__ out)
{
  const int tid = threadIdx.x;
  const long row = blockIdx.x;
  const float* xr = x + row * 768;
  const float v0 = xr[tid], v1 = xr[tid + 256], v2 = xr[tid + 512];
  __shared__ float red[4];
  const int wid = tid >> 6, ln = tid & 63;
  float s = wsum(v0 + v1 + v2);
  if (ln == 0) red[wid] = s;
  __syncthreads();
  const float mean = (red[0] + red[1] + red[2] + red[3]) * (1.0f / 768.0f);
  __syncthreads();
  const float d0 = v0 - mean, d1 = v1 - mean, d2 = v2 - mean;
  float q = wsum(d0 * d0 + d1 * d1 + d2 * d2);
  if (ln == 0) red[wid] = q;
  __syncthreads();
  const float var = (red[0] + red[1] + red[2] + red[3]) * (1.0f / 768.0f);
  const float rs = rsqrtf(var + 1e-5f);
  const float y0 = d0 * rs * g1[tid]       + b1[tid];
  const float y1 = d1 * rs * g1[tid + 256] + b1[tid + 256];
  const float y2 = d2 * rs * g1[tid + 512] + b1[tid + 512];
  __syncthreads();
  float s2 = wsum(y0 + y1 + y2);
  if (ln == 0) red[wid] = s2;
  __syncthreads();
  const float mean2 = (red[0] + red[1] + red[2] + red[3]) * (1.0f / 768.0f);
  __syncthreads();
  const float e0 = y0 - mean2, e1 = y1 - mean2, e2 = y2 - mean2;
  float q2 = wsum(e0 * e0 + e1 * e1 + e2 * e2);
  if (ln == 0) red[wid] = q2;
  __syncthreads();
  const float var2 = (red[0] + red[1] + red[2] + red[3]) * (1.0f / 768.0f);
  const float rs2 = rsqrtf(var2 + 1e-5f);
  unsigned short* o = out + row * 768;
  o[tid]       = f2bf(e0 * rs2 * g2[tid]       + b2[tid]);
  o[tid + 256] = f2bf(e1 * rs2 * g2[tid + 256] + b2[tid + 256]);
  o[tid + 512] = f2bf(e2 * rs2 * g2[tid + 512] + b2[tid + 512]);
}

__global__ __launch_bounds__(256) void lnf_k(
    const float* __restrict__ x, const float* __restrict__ g, const float* __restrict__ b,
    float* __restrict__ out)
{
  const int tid = threadIdx.x;
  const long row = blockIdx.x;
  const float v = x[row * 256 + tid];
  __shared__ float red[4];
  const int wid = tid >> 6, ln = tid & 63;
  float s = wsum(v);
  if (ln == 0) red[wid] = s;
  __syncthreads();
  const float mean = (red[0] + red[1] + red[2] + red[3]) * (1.0f / 256.0f);
  __syncthreads();
  const float d = v - mean;
  float q = wsum(d * d);
  if (ln == 0) red[wid] = q;
  __syncthreads();
  const float var = (red[0] + red[1] + red[2] + red[3]) * (1.0f / 256.0f);
  const float rs = rsqrtf(var + 1e-5f);
  out[row * 256 + tid] = d * rs * g[tid] + b[tid];
}

// ---------------- weight transpose + cast, bias concat ----------------
__global__ __launch_bounds__(256) void tcast_k(
    const float* __restrict__ W, unsigned short* __restrict__ Wt, int K, int N)
{
  __shared__ float t[32][33];
  const int tx = threadIdx.x & 31, ty = threadIdx.x >> 5;
  const int n0 = blockIdx.x * 32, k0 = blockIdx.y * 32;
#pragma unroll
  for (int j = 0; j < 32; j += 8)
    t[ty + j][tx] = W[(long)(k0 + ty + j) * N + n0 + tx];
  __syncthreads();
#pragma unroll
  for (int j = 0; j < 32; j += 8)
    Wt[(long)(n0 + ty + j) * K + k0 + tx] = f2bf(t[tx][ty + j]);
}

__global__ __launch_bounds__(256) void cat3_k(
    const float* __restrict__ a, const float* __restrict__ b, const float* __restrict__ c,
    float* __restrict__ dst)
{
  const int i = blockIdx.x * 256 + threadIdx.x;   // grid 9 -> 2304
  dst[i] = (i < 768) ? a[i] : (i < 1536 ? b[i - 768] : c[i - 1536]);
}

// ---------------- launcher ----------------
extern "C" void kernel_launch(void* const* d_in, const int* in_sizes, int n_in,
                              void* d_out, int out_size, void* d_ws, size_t ws_size,
                              hipStream_t stream)
{
  const float* x    = (const float*)d_in[0];
  const int*   mask = (const int*)d_in[1];
  const float* n1g = (const float*)d_in[2];  const float* n1b = (const float*)d_in[3];
  const float* wq  = (const float*)d_in[4];  const float* bq  = (const float*)d_in[5];
  const float* wk  = (const float*)d_in[6];  const float* bk  = (const float*)d_in[7];
  const float* wv  = (const float*)d_in[8];  const float* bv  = (const float*)d_in[9];
  const float* wo  = (const float*)d_in[10]; const float* bo  = (const float*)d_in[11];
  const float* n2g = (const float*)d_in[12]; const float* n2b = (const float*)d_in[13];
  const float* w1  = (const float*)d_in[14]; const float* b1  = (const float*)d_in[15];
  const float* w2  = (const float*)d_in[16]; const float* b2  = (const float*)d_in[17];
  const float* pwq = (const float*)d_in[18]; const float* pbq = (const float*)d_in[19];
  const float* pwk = (const float*)d_in[20]; const float* pbk = (const float*)d_in[21];
  const float* pwv = (const float*)d_in[22]; const float* pbv = (const float*)d_in[23];
  const float* pwo = (const float*)d_in[24]; const float* pbo = (const float*)d_in[25];
  const float* png = (const float*)d_in[26]; const float* pnb = (const float*)d_in[27];
  const float* tng = (const float*)d_in[28]; const float* tnb = (const float*)d_in[29];
  const float* pjw = (const float*)d_in[30]; const float* pjb = (const float*)d_in[31];
  const float* ong = (const float*)d_in[32]; const float* onb = (const float*)d_in[33];
  float* out = (float*)d_out;

  char* p = (char*)d_ws;
  auto alloc = [&](size_t n) { void* r = (void*)p; p += (n + 255) & ~(size_t)255; return r; };

  unsigned short* wqkvt = (unsigned short*)alloc((size_t)3 * HID * HID * 2);  // 2304 x 768
  unsigned short* wot   = (unsigned short*)alloc((size_t)HID * HID * 2);
  unsigned short* w1t   = (unsigned short*)alloc((size_t)FFND * HID * 2);
  unsigned short* w2t   = (unsigned short*)alloc((size_t)HID * FFND * 2);
  unsigned short* pqkvt = (unsigned short*)alloc((size_t)3 * HID * HID * 2);
  unsigned short* pwot  = (unsigned short*)alloc((size_t)HID * 2 * HID * 2);
  unsigned short* pjwt  = (unsigned short*)alloc((size_t)EOUTD * HID * 2);
  float*          qkvbias = (float*)alloc((size_t)3 * HID * 4);
  float*          pqkvbias= (float*)alloc((size_t)3 * HID * 4);
  unsigned short* bfA   = (unsigned short*)alloc((size_t)TOK * HID * 2);      // h1 -> h -> x3
  unsigned short* QKVb  = (unsigned short*)alloc((size_t)TOK * 3 * HID * 2);  // 65536 x 2304; FFN hidden alias
  unsigned short* bfB   = (unsigned short*)alloc((size_t)TOK * HID * 2);      // attn out
  unsigned short* x2b   = (unsigned short*)alloc((size_t)TOK * HID * 2);      // x2 (bf16)
  unsigned short* fusedb= (unsigned short*)alloc((size_t)BATCH * 2 * HID * 2);
  float*          qresb = (float*)alloc((size_t)BATCH * HID * 4);
  float*          preln = (float*)alloc((size_t)BATCH * HID * 4);
  unsigned short* pooledb=(unsigned short*)alloc((size_t)BATCH * HID * 2);
  float*          news  = (float*)alloc((size_t)BATCH * EOUTD * 4);
  (void)ws_size; (void)in_sizes; (void)n_in; (void)out_size;

  // weight prep
  tcast_k<<<dim3(HID/32,  HID/32),  256, 0, stream>>>(wq,  wqkvt,                 HID, HID);
  tcast_k<<<dim3(HID/32,  HID/32),  256, 0, stream>>>(wk,  wqkvt + (size_t)HID*HID,   HID, HID);
  tcast_k<<<dim3(HID/32,  HID/32),  256, 0, stream>>>(wv,  wqkvt + (size_t)2*HID*HID, HID, HID);
  tcast_k<<<dim3(HID/32,  HID/32),  256, 0, stream>>>(wo,  wot,  HID,  HID);
  tcast_k<<<dim3(FFND/32, HID/32),  256, 0, stream>>>(w1,  w1t,  HID,  FFND);
  tcast_k<<<dim3(HID/32,  FFND/32), 256, 0, stream>>>(w2,  w2t,  FFND, HID);
  tcast_k<<<dim3(HID/32,  HID/32),  256, 0, stream>>>(pwq, pqkvt,                 HID, HID);
  tcast_k<<<dim3(HID/32,  HID/32),  256, 0, stream>>>(pwk, pqkvt + (size_t)HID*HID,   HID, HID);
  tcast_k<<<dim3(HID/32,  HID/32),  256, 0, stream>>>(pwv, pqkvt + (size_t)2*HID*HID, HID, HID);
  tcast_k<<<dim3(HID/32,  (2*HID)/32), 256, 0, stream>>>(pwo, pwot, 2*HID, HID);
  tcast_k<<<dim3(EOUTD/32, HID/32), 256, 0, stream>>>(pjw, pjwt, HID,  EOUTD);
  cat3_k<<<9, 256, 0, stream>>>(bq,  bk,  bv,  qkvbias);
  cat3_k<<<9, 256, 0, stream>>>(pbq, pbk, pbv, pqkvbias);

  // LN1
  ln768_k<<<TOK, 256, 0, stream>>>(x, n1g, n1b, bfA);

  // fused QKV GEMM: 65536 x 2304, K=768  [128^2, proven]
  gemm_k<EPI_OUTB><<<(TOK/128)*(3*HID/128), 256, 0, stream>>>(
      bfA, wqkvt, qkvbias, nullptr, nullptr, nullptr, QKVb, TOK, 3*HID, HID);

  // fastformer attention -> bfB (stride 768)
  fastattn2_k<false><<<BATCH * NHEAD / 4, 256, 0, stream>>>(
      QKVb, QKVb + HID, QKVb + 2*HID, 3*HID, mask, bfB, nullptr, nullptr);

  // wo proj + f32 resid x -> x2 (bf16)   [128^2]
  gemm_k<EPI_OUTB | EPI_RESF><<<(TOK/128)*(HID/128), 256, 0, stream>>>(
      bfB, wot, bo, x, nullptr, nullptr, x2b, TOK, HID, HID);

  // LN2 (bf16 in)
  ln768b_k<<<TOK, 256, 0, stream>>>(x2b, n2g, n2b, bfA);

  // FFN in 2 row-chunks of 32768; hidden lives in QKVb (dead until pool QKV)  [128^2]
  for (int c = 0; c < 2; c++) {
    const size_t ro = (size_t)c * 32768;
    gemm_k<EPI_OUTB | EPI_GELU><<<(32768/128)*(FFND/128), 256, 0, stream>>>(
        bfA + ro * HID, w1t, b1, nullptr, nullptr, nullptr, QKVb, 32768, FFND, HID);
    gemm_k<EPI_OUTB | EPI_RESB><<<(32768/128)*(HID/128), 256, 0, stream>>>(
        QKVb, w2t, b2, nullptr, x2b + ro * HID, nullptr, bfA + ro * HID, 32768, HID, FFND);
  }
  // bfA = x3 (bf16)

  // fused pool QKV GEMM  [128^2]
  gemm_k<EPI_OUTB><<<(TOK/128)*(3*HID/128), 256, 0, stream>>>(
      bfA, pqkvt, pqkvbias, nullptr, nullptr, nullptr, QKVb, TOK, 3*HID, HID);

  // pooling core
  fastattn2_k<true><<<BATCH * NHEAD / 4, 256, 0, stream>>>(
      QKVb, QKVb + HID, QKVb + 2*HID, 3*HID, mask, nullptr, fusedb, qresb);

  // pool out proj (+qres) -> preln f32  [128^2]
  gemm_k<EPI_OUTF | EPI_RESF><<<(BATCH/128)*(HID/128), 256, 0, stream>>>(
      fusedb, pwot, pbo, qresb, nullptr, preln, nullptr, BATCH, HID, 2*HID);

  // double LN -> pooled bf16
  ln2x_k<<<BATCH, 256, 0, stream>>>(preln, png, pnb, tng, tnb, pooledb);

  // proj -> news f32  [128^2]
  gemm_k<EPI_OUTF><<<(BATCH/128)*(EOUTD/128), 256, 0, stream>>>(
      pooledb, pjwt, pjb, nullptr, nullptr, news, nullptr, BATCH, EOUTD, HID);

  // final LN
  lnf_k<<<BATCH, 256, 0, stream>>>(news, ong, onb, out);
}

// Round 18
// 2088.337 us; speedup vs baseline: 1.2863x; 1.0242x over previous
//
#include <hip/hip_runtime.h>
#include <math.h>

// ---------------- configuration ----------------
#define NHEAD 8
#define HID   768
#define FFND  3072
#define EOUTD 256
#define BATCH 1024
#define TOK   (BATCH*64)   // 65536

#define EPI_RESF  1
#define EPI_RESB  2
#define EPI_GELU  4
#define EPI_OUTF  8
#define EPI_OUTB  16

typedef __attribute__((ext_vector_type(8))) short short8;   // 8 x bf16
typedef __attribute__((ext_vector_type(4))) float f32x4;    // MFMA C/D

#define AS1 __attribute__((address_space(1)))
#define AS3 __attribute__((address_space(3)))

__device__ __forceinline__ void async16(const void* g, void* l) {
  __builtin_amdgcn_global_load_lds(
      (AS1 unsigned int*)(unsigned long long)g,
      (AS3 unsigned int*)(unsigned int)(unsigned long long)l,
      16, 0, 0);
}

__device__ __forceinline__ float bf2f(unsigned short u) {
  union { unsigned int i; float f; } c; c.i = ((unsigned int)u) << 16; return c.f;
}
__device__ __forceinline__ unsigned short f2bf(float f) {
  union { float f; unsigned int i; } c; c.f = f;
  unsigned int x = c.i + 0x7fffu + ((c.i >> 16) & 1u);   // RNE
  return (unsigned short)(x >> 16);
}
__device__ __forceinline__ float wsum(float v) {
#pragma unroll
  for (int o = 32; o > 0; o >>= 1) v += __shfl_xor(v, o);
  return v;
}
// GELU with fast erf (Abramowitz-Stegun 7.1.26, |err| < 1.5e-7)
__device__ __forceinline__ float gelu_f(float v) {
  const float z = fabsf(v) * 0.70710678118654752f;
  const float t = 1.0f / (1.0f + 0.3275911f * z);
  const float poly = t * (0.254829592f + t * (-0.284496736f +
                     t * (1.421413741f + t * (-1.453152027f + t * 1.061405429f))));
  float erfv = 1.0f - poly * __expf(-z * z);
  erfv = (v < 0.f) ? -erfv : erfv;
  return 0.5f * v * (1.0f + erfv);
}

// ---------------- GEMM 128x128 (proven workhorse; ~800 TF, m97-structure) ----------------
// HISTORY (do not regress): 256^2 8-phase attempts both LOST on HW:
//  R4 (memory-clobber fences): waitcnt pass inserted vmcnt(0) drains at every
//     barrier while LDS-DMA outstanding -> 358us @ 27.8% MfmaUtil.
//  R12 (volatile-asm ds_reads + sched_barrier(0) pinning): scheduler/allocator
//     defeated -> scratch spills (FETCH 266->641MB, WRITE 433->581MB) ->
//     752us @ 12.6% MfmaUtil. Guide m141 failure mode.
// The 128^2 2-barrier kernel at 290us/36% MfmaUtil is the verified optimum
// for this toolchain at these shapes.
template<int EPI>
__global__ __launch_bounds__(256, 3) void gemm_k(
    const unsigned short* __restrict__ A, const unsigned short* __restrict__ Wt,
    const float* __restrict__ bias,
    const float* __restrict__ residF, const unsigned short* __restrict__ residB,
    float* __restrict__ outF, unsigned short* __restrict__ outB,
    int M, int N, int K)
{
  __shared__ unsigned short lA[128 * 64];
  __shared__ unsigned short lB[128 * 64];
  const int tid  = threadIdx.x;

  const int nT  = N >> 7;
  const int per = gridDim.x >> 3;
  const int tile = (blockIdx.x & 7) * per + (blockIdx.x >> 3);
  int m_idx = tile / nT;
  int n_idx = tile - m_idx * nT;
  if (m_idx & 1) n_idx = nT - 1 - n_idx;
  const int n0 = n_idx * 128;
  const int m0 = m_idx * 128;

  const int lane = tid & 63;
  const int wid  = tid >> 6;
  const int wm   = wid & 1, wn = wid >> 1;
  const int m16  = lane & 15, quad = lane >> 4;

  f32x4 zero = {0.0f, 0.0f, 0.0f, 0.0f};
  f32x4 acc[4][4];
#pragma unroll
  for (int i = 0; i < 4; i++)
#pragma unroll
    for (int j = 0; j < 4; j++) acc[i][j] = zero;

  long aoff[4], boff[4];
#pragma unroll
  for (int j = 0; j < 4; j++) {
    const int L = tid + j * 256;
    const int row = L >> 3;
    const int kc  = (L & 7) ^ (row & 7);
    aoff[j] = (long)(m0 + row) * K + kc * 8;
    boff[j] = (long)(n0 + row) * K + kc * 8;
  }

  for (int k0 = 0; k0 < K; k0 += 64) {
#pragma unroll
    for (int j = 0; j < 4; j++)
      async16(A + aoff[j] + k0, lA + (size_t)(j * 256 + wid * 64) * 8);
#pragma unroll
    for (int j = 0; j < 4; j++)
      async16(Wt + boff[j] + k0, lB + (size_t)(j * 256 + wid * 64) * 8);
    __syncthreads();
#pragma unroll
    for (int s = 0; s < 2; s++) {
      short8 af[4], bfr[4];
#pragma unroll
      for (int mi = 0; mi < 4; mi++) {
        const int row = wm * 64 + mi * 16 + m16;
        const int kc  = (s * 4 + quad) ^ (row & 7);
        af[mi] = *(const short8*)(lA + row * 64 + kc * 8);
      }
#pragma unroll
      for (int ni = 0; ni < 4; ni++) {
        const int row = wn * 64 + ni * 16 + m16;
        const int kc  = (s * 4 + quad) ^ (row & 7);
        bfr[ni] = *(const short8*)(lB + row * 64 + kc * 8);
      }
#pragma unroll
      for (int mi = 0; mi < 4; mi++)
#pragma unroll
        for (int ni = 0; ni < 4; ni++)
          acc[mi][ni] = __builtin_amdgcn_mfma_f32_16x16x32_bf16(bfr[ni], af[mi], acc[mi][ni], 0, 0, 0);
    }
    __syncthreads();
  }

#pragma unroll
  for (int mi = 0; mi < 4; mi++) {
    const int m = m0 + wm * 64 + mi * 16 + m16;
    const long rb = (long)m * N;
#pragma unroll
    for (int ni = 0; ni < 4; ni++) {
      const int nb = n0 + wn * 64 + ni * 16 + quad * 4;
      f32x4 v = acc[mi][ni];
      const f32x4 bi = *(const f32x4*)(bias + nb);
#pragma unroll
      for (int r = 0; r < 4; r++) v[r] += bi[r];
      if (EPI & EPI_RESF) {
        const f32x4 rf = *(const f32x4*)(residF + rb + nb);
#pragma unroll
        for (int r = 0; r < 4; r++) v[r] += rf[r];
      }
      if (EPI & EPI_RESB) {
        const unsigned long long rv = *(const unsigned long long*)(residB + rb + nb);
#pragma unroll
        for (int r = 0; r < 4; r++) v[r] += bf2f((unsigned short)(rv >> (16 * r)));
      }
      if (EPI & EPI_GELU) {
#pragma unroll
        for (int r = 0; r < 4; r++) v[r] = gelu_f(v[r]);
      }
      if (EPI & EPI_OUTF) *(f32x4*)(outF + rb + nb) = v;
      if (EPI & EPI_OUTB) {
        unsigned long long o = 0;
#pragma unroll
        for (int r = 0; r < 4; r++) o |= (unsigned long long)f2bf(v[r]) << (16 * r);
        *(unsigned long long*)(outB + rb + nb) = o;
      }
    }
  }
}

// ---------------- Fastformer attention / pooling: MFMA Gram-matrix version ----------------
template<bool POOL>
__global__ __launch_bounds__(256) void fastattn2_k(
    const unsigned short* __restrict__ Q,
    const unsigned short* __restrict__ Kx,
    const unsigned short* __restrict__ V,
    int ld,
    const int* __restrict__ mask,
    unsigned short* __restrict__ attnO,
    unsigned short* __restrict__ fused,
    float* __restrict__ qres)
{
  const int lane = threadIdx.x & 63;
  const int wid  = threadIdx.x >> 6;
  const int gw   = blockIdx.x * 4 + wid;
  const int b = gw >> 3, h = gw & 7;
  const int c = lane & 15, quad = lane >> 4;
  const unsigned short* Qp = Q  + (long)b * 64 * ld + h * 96;
  const unsigned short* Kp = Kx + (long)b * 64 * ld + h * 96;
  const unsigned short* Vp = V  + (long)b * 64 * ld + h * 96;
  const float mval = (mask[b * 64 + lane] != 0) ? 1.0f : 0.0f;

  f32x4 G[4][4];
  f32x4 zero = {0.f, 0.f, 0.f, 0.f};
#pragma unroll
  for (int mi = 0; mi < 4; mi++)
#pragma unroll
    for (int ni = 0; ni < 4; ni++) G[mi][ni] = zero;
  float ql[4] = {0.f, 0.f, 0.f, 0.f};

#pragma unroll
  for (int kc = 0; kc < 3; kc++) {
    const int dcol = kc * 32 + quad * 8;
    short8 afr[4], bfr[4];
#pragma unroll
    for (int mi = 0; mi < 4; mi++)
      afr[mi] = *(const short8*)(Kp + (long)(mi * 16 + c) * ld + dcol);
#pragma unroll
    for (int ni = 0; ni < 4; ni++)
      bfr[ni] = *(const short8*)(Qp + (long)(ni * 16 + c) * ld + dcol);
#pragma unroll
    for (int ni = 0; ni < 4; ni++) {
      float t = 0.f;
#pragma unroll
      for (int j = 0; j < 8; j++) t += bf2f((unsigned short)bfr[ni][j]);
      ql[ni] += t;
    }
#pragma unroll
    for (int mi = 0; mi < 4; mi++)
#pragma unroll
      for (int ni = 0; ni < 4; ni++)
        G[mi][ni] = __builtin_amdgcn_mfma_f32_16x16x32_bf16(afr[mi], bfr[ni], G[mi][ni], 0, 0, 0);
  }
#pragma unroll
  for (int ni = 0; ni < 4; ni++) {
    ql[ni] += __shfl_xor(ql[ni], 16);
    ql[ni] += __shfl_xor(ql[ni], 32);
  }

  float qw[4];
  {
    float lg[4], mx = -3.4e38f;
#pragma unroll
    for (int ni = 0; ni < 4; ni++) {
      const float mk = __shfl(mval, ni * 16 + c);
      lg[ni] = (mk > 0.5f) ? ql[ni] * 0.102062072615966f : -10000.0f;
      mx = fmaxf(mx, lg[ni]);
    }
#pragma unroll
    for (int o = 1; o <= 8; o <<= 1) mx = fmaxf(mx, __shfl_xor(mx, o));
    float se = 0.f;
#pragma unroll
    for (int ni = 0; ni < 4; ni++) { qw[ni] = expf(lg[ni] - mx); se += qw[ni]; }
#pragma unroll
    for (int o = 1; o <= 8; o <<= 1) se += __shfl_xor(se, o);
    const float inv = 1.0f / se;
#pragma unroll
    for (int ni = 0; ni < 4; ni++) qw[ni] *= inv;
  }

  float kw[16];
#pragma unroll
  for (int mi = 0; mi < 4; mi++)
#pragma unroll
    for (int r = 0; r < 4; r++) {
      float a = 0.f;
#pragma unroll
      for (int ni = 0; ni < 4; ni++) a += G[mi][ni][r] * qw[ni];
      kw[mi * 4 + r] = a;
    }
#pragma unroll
  for (int i = 0; i < 16; i++)
#pragma unroll
    for (int o = 1; o <= 8; o <<= 1) kw[i] += __shfl_xor(kw[i], o);

  {
    float mx2 = -3.4e38f;
#pragma unroll
    for (int i = 0; i < 16; i++) {
      const int mi = i >> 2, r = i & 3;
      const float mk = __shfl(mval, mi * 16 + quad * 4 + r);
      kw[i] = (mk > 0.5f) ? kw[i] : -10000.0f;
      mx2 = fmaxf(mx2, kw[i]);
    }
    mx2 = fmaxf(mx2, __shfl_xor(mx2, 16));
    mx2 = fmaxf(mx2, __shfl_xor(mx2, 32));
    float se2 = 0.f;
#pragma unroll
    for (int i = 0; i < 16; i++) { kw[i] = expf(kw[i] - mx2); se2 += kw[i]; }
    se2 += __shfl_xor(se2, 16);
    se2 += __shfl_xor(se2, 32);
    const float inv = 1.0f / se2;
#pragma unroll
    for (int i = 0; i < 16; i++) kw[i] *= inv;
  }

  float vw[4];
  {
    float vl[4] = {0.f, 0.f, 0.f, 0.f};
#pragma unroll
    for (int ni = 0; ni < 4; ni++) {
#pragma unroll
      for (int mi = 0; mi < 4; mi++)
#pragma unroll
        for (int r = 0; r < 4; r++) vl[ni] += G[mi][ni][r] * kw[mi * 4 + r];
      vl[ni] += __shfl_xor(vl[ni], 16);
      vl[ni] += __shfl_xor(vl[ni], 32);
    }
    float mx = -3.4e38f;
#pragma unroll
    for (int ni = 0; ni < 4; ni++) {
      const float mk = __shfl(mval, ni * 16 + c);
      vl[ni] = (mk > 0.5f) ? vl[ni] : -10000.0f;
      mx = fmaxf(mx, vl[ni]);
    }
#pragma unroll
    for (int o = 1; o <= 8; o <<= 1) mx = fmaxf(mx, __shfl_xor(mx, o));
    float se = 0.f;
#pragma unroll
    for (int ni = 0; ni < 4; ni++) { vw[ni] = expf(vl[ni] - mx); se += vw[ni]; }
#pragma unroll
    for (int o = 1; o <= 8; o <<= 1) se += __shfl_xor(se, o);
    const float inv = 1.0f / se;
#pragma unroll
    for (int ni = 0; ni < 4; ni++) vw[ni] *= inv;
  }

  if (!POOL) {
    __shared__ float swv[4][64];
    if (quad == 0) {
#pragma unroll
      for (int ni = 0; ni < 4; ni++) swv[wid][ni * 16 + c] = vw[ni];
    }
    __syncthreads();
    unsigned short* Op = attnO + (long)b * 64 * 768 + h * 96;
#pragma unroll
    for (int it = 0; it < 12; it++) {
      const int idx = it * 64 + lane;
      const int s = idx / 12, cw = idx % 12;
      short8 v = *(const short8*)(Vp + (long)s * ld + cw * 8);
      const float w = swv[wid][s];
      short8 o;
#pragma unroll
      for (int j = 0; j < 8; j++) o[j] = (short)f2bf(w * bf2f((unsigned short)v[j]));
      *(short8*)(Op + (long)s * 768 + cw * 8) = o;
    }
  } else {
    float qg[24], vg[24];
#pragma unroll
    for (int kc = 0; kc < 3; kc++) {
      const int dcol = kc * 32 + quad * 8;
      short8 fq[4], fv[4];
#pragma unroll
      for (int ni = 0; ni < 4; ni++) {
        fq[ni] = *(const short8*)(Qp + (long)(ni * 16 + c) * ld + dcol);
        fv[ni] = *(const short8*)(Vp + (long)(ni * 16 + c) * ld + dcol);
      }
#pragma unroll
      for (int j = 0; j < 8; j++) {
        float aq = 0.f, av = 0.f;
#pragma unroll
        for (int ni = 0; ni < 4; ni++) {
          aq += qw[ni] * bf2f((unsigned short)fq[ni][j]);
          av += vw[ni] * bf2f((unsigned short)fv[ni][j]);
        }
        qg[kc * 8 + j] = aq; vg[kc * 8 + j] = av;
      }
    }
#pragma unroll
    for (int i = 0; i < 24; i++) {
#pragma unroll
      for (int o = 1; o <= 8; o <<= 1) {
        qg[i] += __shfl_xor(qg[i], o);
        vg[i] += __shfl_xor(vg[i], o);
      }
    }
    if (c == 0) {
#pragma unroll
      for (int kc = 0; kc < 3; kc++)
#pragma unroll
        for (int j = 0; j < 8; j++) {
          const int d = kc * 32 + quad * 8 + j;
          const float qv = qg[kc * 8 + j], vv = vg[kc * 8 + j];
          fused[(long)b * 1536 + d * 8 + h]        = f2bf(qv);
          fused[(long)b * 1536 + (96 + d) * 8 + h] = f2bf(vv);
          qres[(long)b * 768 + d * 8 + h] = qv;
        }
    }
  }
}

// ---------------- LayerNorms ----------------
__global__ __launch_bounds__(256) void ln768_k(
    const float* __restrict__ x, const float* __restrict__ g, const float* __restrict__ b,
    unsigned short* __restrict__ out)
{
  const int tid = threadIdx.x;
  const long row = blockIdx.x;
  const float* xr = x + row * 768;
  const float v0 = xr[tid], v1 = xr[tid + 256], v2 = xr[tid + 512];
  __shared__ float red[4];
  const int wid = tid >> 6, ln = tid & 63;
  float s = wsum(v0 + v1 + v2);
  if (ln == 0) red[wid] = s;
  __syncthreads();
  const float mean = (red[0] + red[1] + red[2] + red[3]) * (1.0f / 768.0f);
  __syncthreads();
  const float d0 = v0 - mean, d1 = v1 - mean, d2 = v2 - mean;
  float q = wsum(d0 * d0 + d1 * d1 + d2 * d2);
  if (ln == 0) red[wid] = q;
  __syncthreads();
  const float var = (red[0] + red[1] + red[2] + red[3]) * (1.0f / 768.0f);
  const float rs = rsqrtf(var + 1e-5f);
  unsigned short* o = out + row * 768;
  o[tid]       = f2bf(d0 * rs * g[tid]       + b[tid]);
  o[tid + 256] = f2bf(d1 * rs * g[tid + 256] + b[tid + 256]);
  o[tid + 512] = f2bf(d2 * rs * g[tid + 512] + b[tid + 512]);
}

__global__ __launch_bounds__(256) void ln768b_k(
    const unsigned short* __restrict__ x, const float* __restrict__ g, const float* __restrict__ b,
    unsigned short* __restrict__ out)
{
  const int tid = threadIdx.x;
  const long row = blockIdx.x;
  const unsigned short* xr = x + row * 768;
  const float v0 = bf2f(xr[tid]), v1 = bf2f(xr[tid + 256]), v2 = bf2f(xr[tid + 512]);
  __shared__ float red[4];
  const int wid = tid >> 6, ln = tid & 63;
  float s = wsum(v0 + v1 + v2);
  if (ln == 0) red[wid] = s;
  __syncthreads();
  const float mean = (red[0] + red[1] + red[2] + red[3]) * (1.0f / 768.0f);
  __syncthreads();
  const float d0 = v0 - mean, d1 = v1 - mean, d2 = v2 - mean;
  float q = wsum(d0 * d0 + d1 * d1 + d2 * d2);
  if (ln == 0) red[wid] = q;
  __syncthreads();
  const float var = (red[0] + red[1] + red[2] + red[3]) * (1.0f / 768.0f);
  const float rs = rsqrtf(var + 1e-5f);
  unsigned short* o = out + row * 768;
  o[tid]       = f2bf(d0 * rs * g[tid]       + b[tid]);
  o[tid + 256] = f2bf(d1 * rs * g[tid + 256] + b[tid + 256]);
  o[tid + 512] = f2bf(d2 * rs * g[tid + 512] + b[tid + 512]);
}

__global__ __launch_bounds__(256) void ln2x_k(
    const float* __restrict__ x,
    const float* __restrict__ g1, const float* __restrict__ b1,
    const float* __restrict__ g2, const float* __restrict__ b2,
    unsigned short* __restrict__ out)
{
  const int tid = threadIdx.x;
  const long row = blockIdx.x;
  const float* xr = x + row * 768;
  const float v0 = xr[tid], v1 = xr[tid + 256], v2 = xr[tid + 512];
  __shared__ float red[4];
  const int wid = tid >> 6, ln = tid & 63;
  float s = wsum(v0 + v1 + v2);
  if (ln == 0) red[wid] = s;
  __syncthreads();
  const float mean = (red[0] + red[1] + red[2] + red[3]) * (1.0f / 768.0f);
  __syncthreads();
  const float d0 = v0 - mean, d1 = v1 - mean, d2 = v2 - mean;
  float q = wsum(d0 * d0 + d1 * d1 + d2 * d2);
  if (ln == 0) red[wid] = q;
  __syncthreads();
  const float var = (red[0] + red[1] + red[2] + red[3]) * (1.0f / 768.0f);
  const float rs = rsqrtf(var + 1e-5f);
  const float y0 = d0 * rs * g1[tid]       + b1[tid];
  const float y1 = d1 * rs * g1[tid + 256] + b1[tid + 256];
  const float y2 = d2 * rs * g1[tid + 512] + b1[tid + 512];
  __syncthreads();
  float s2 = wsum(y0 + y1 + y2);
  if (ln == 0) red[wid] = s2;
  __syncthreads();
  const float mean2 = (red[0] + red[1] + red[2] + red[3]) * (1.0f / 768.0f);
  __syncthreads();
  const float e0 = y0 - mean2, e1 = y1 - mean2, e2 = y2 - mean2;
  float q2 = wsum(e0 * e0 + e1 * e1 + e2 * e2);
  if (ln == 0) red[wid] = q2;
  __syncthreads();
  const float var2 = (red[0] + red[1] + red[2] + red[3]) * (1.0f / 768.0f);
  const float rs2 = rsqrtf(var2 + 1e-5f);
  unsigned short* o = out + row * 768;
  o[tid]       = f2bf(e0 * rs2 * g2[tid]       + b2[tid]);
  o[tid + 256] = f2bf(e1 * rs2 * g2[tid + 256] + b2[tid + 256]);
  o[tid + 512] = f2bf(e2 * rs2 * g2[tid + 512] + b2[tid + 512]);
}

__global__ __launch_bounds__(256) void lnf_k(
    const float* __restrict__ x, const float* __restrict__ g, const float* __restrict__ b,
    float* __restrict__ out)
{
  const int tid = threadIdx.x;
  const long row = blockIdx.x;
  const float v = x[row * 256 + tid];
  __shared__ float red[4];
  const int wid = tid >> 6, ln = tid & 63;
  float s = wsum(v);
  if (ln == 0) red[wid] = s;
  __syncthreads();
  const float mean = (red[0] + red[1] + red[2] + red[3]) * (1.0f / 256.0f);
  __syncthreads();
  const float d = v - mean;
  float q = wsum(d * d);
  if (ln == 0) red[wid] = q;
  __syncthreads();
  const float var = (red[0] + red[1] + red[2] + red[3]) * (1.0f / 256.0f);
  const float rs = rsqrtf(var + 1e-5f);
  out[row * 256 + tid] = d * rs * g[tid] + b[tid];
}

// ---------------- fused weight prep: 11 transposes + 2 bias concats in ONE dispatch ----------
// Flat grid: 9984 transpose tiles (32x32, ranges below) + 18 concat blocks.
// Per-tile math is bit-identical to the old tcast_k / cat3_k.
//  range [0,576)      wq  -> wqkvt          K=768  N=768   ntx=24
//  [576,1152)         wk  -> wqkvt+589824
//  [1152,1728)        wv  -> wqkvt+1179648
//  [1728,2304)        wo  -> wot
//  [2304,4608)        w1  -> w1t            K=768  N=3072  ntx=96
//  [4608,6912)        w2  -> w2t            K=3072 N=768   ntx=24
//  [6912,7488)        pwq -> pqkvt
//  [7488,8064)        pwk -> pqkvt+589824
//  [8064,8640)        pwv -> pqkvt+1179648
//  [8640,9792)        pwo -> pwot           K=1536 N=768   ntx=24
//  [9792,9984)        pjw -> pjwt           K=768  N=256   ntx=8
//  [9984,9993)        cat3(bq,bk,bv)->qkvbias
//  [9993,10002)       cat3(pbq,pbk,pbv)->pqkvbias
__global__ __launch_bounds__(256) void prep_k(
    const float* __restrict__ wq,  const float* __restrict__ wk,
    const float* __restrict__ wv,  const float* __restrict__ wo,
    const float* __restrict__ w1,  const float* __restrict__ w2,
    const float* __restrict__ pwq, const float* __restrict__ pwk,
    const float* __restrict__ pwv, const float* __restrict__ pwo,
    const float* __restrict__ pjw,
    unsigned short* __restrict__ wqkvt, unsigned short* __restrict__ wot,
    unsigned short* __restrict__ w1t,   unsigned short* __restrict__ w2t,
    unsigned short* __restrict__ pqkvt, unsigned short* __restrict__ pwot,
    unsigned short* __restrict__ pjwt,
    const float* __restrict__ bq,  const float* __restrict__ bk,
    const float* __restrict__ bv,  const float* __restrict__ pbq,
    const float* __restrict__ pbk, const float* __restrict__ pbv,
    float* __restrict__ qkvbias, float* __restrict__ pqkvbias)
{
  const int bid = blockIdx.x;
  if (bid >= 9984) {
    // concat blocks (whole block takes this path; no barrier divergence)
    int cb = bid - 9984;
    const float *a, *b, *c; float* dst;
    if (cb < 9) { a = bq;  b = bk;  c = bv;  dst = qkvbias; }
    else        { cb -= 9; a = pbq; b = pbk; c = pbv; dst = pqkvbias; }
    const int i = cb * 256 + threadIdx.x;   // 9 blocks -> 2304
    dst[i] = (i < 768) ? a[i] : (i < 1536 ? b[i - 768] : c[i - 1536]);
    return;
  }

  const float* W; unsigned short* Wt; int K, N, t0;
  if      (bid < 576)  { W = wq;  Wt = wqkvt;           K = 768;  N = 768;  t0 = 0;    }
  else if (bid < 1152) { W = wk;  Wt = wqkvt + 589824;  K = 768;  N = 768;  t0 = 576;  }
  else if (bid < 1728) { W = wv;  Wt = wqkvt + 1179648; K = 768;  N = 768;  t0 = 1152; }
  else if (bid < 2304) { W = wo;  Wt = wot;             K = 768;  N = 768;  t0 = 1728; }
  else if (bid < 4608) { W = w1;  Wt = w1t;             K = 768;  N = 3072; t0 = 2304; }
  else if (bid < 6912) { W = w2;  Wt = w2t;             K = 3072; N = 768;  t0 = 4608; }
  else if (bid < 7488) { W = pwq; Wt = pqkvt;           K = 768;  N = 768;  t0 = 6912; }
  else if (bid < 8064) { W = pwk; Wt = pqkvt + 589824;  K = 768;  N = 768;  t0 = 7488; }
  else if (bid < 8640) { W = pwv; Wt = pqkvt + 1179648; K = 768;  N = 768;  t0 = 8064; }
  else if (bid < 9792) { W = pwo; Wt = pwot;            K = 1536; N = 768;  t0 = 8640; }
  else                 { W = pjw; Wt = pjwt;            K = 768;  N = 256;  t0 = 9792; }

  __shared__ float t[32][33];
  const int tx = threadIdx.x & 31, ty = threadIdx.x >> 5;
  const int tt  = bid - t0;
  const int ntx = N >> 5;
  const int n0 = (tt % ntx) * 32, k0 = (tt / ntx) * 32;
#pragma unroll
  for (int j = 0; j < 32; j += 8)
    t[ty + j][tx] = W[(long)(k0 + ty + j) * N + n0 + tx];
  __syncthreads();
#pragma unroll
  for (int j = 0; j < 32; j += 8)
    Wt[(long)(n0 + ty + j) * K + k0 + tx] = f2bf(t[tx][ty + j]);
}

// ---------------- launcher ----------------
extern "C" void kernel_launch(void* const* d_in, const int* in_sizes, int n_in,
                              void* d_out, int out_size, void* d_ws, size_t ws_size,
                              hipStream_t stream)
{
  const float* x    = (const float*)d_in[0];
  const int*   mask = (const int*)d_in[1];
  const float* n1g = (const float*)d_in[2];  const float* n1b = (const float*)d_in[3];
  const float* wq  = (const float*)d_in[4];  const float* bq  = (const float*)d_in[5];
  const float* wk  = (const float*)d_in[6];  const float* bk  = (const float*)d_in[7];
  const float* wv  = (const float*)d_in[8];  const float* bv  = (const float*)d_in[9];
  const float* wo  = (const float*)d_in[10]; const float* bo  = (const float*)d_in[11];
  const float* n2g = (const float*)d_in[12]; const float* n2b = (const float*)d_in[13];
  const float* w1  = (const float*)d_in[14]; const float* b1  = (const float*)d_in[15];
  const float* w2  = (const float*)d_in[16]; const float* b2  = (const float*)d_in[17];
  const float* pwq = (const float*)d_in[18]; const float* pbq = (const float*)d_in[19];
  const float* pwk = (const float*)d_in[20]; const float* pbk = (const float*)d_in[21];
  const float* pwv = (const float*)d_in[22]; const float* pbv = (const float*)d_in[23];
  const float* pwo = (const float*)d_in[24]; const float* pbo = (const float*)d_in[25];
  const float* png = (const float*)d_in[26]; const float* pnb = (const float*)d_in[27];
  const float* tng = (const float*)d_in[28]; const float* tnb = (const float*)d_in[29];
  const float* pjw = (const float*)d_in[30]; const float* pjb = (const float*)d_in[31];
  const float* ong = (const float*)d_in[32]; const float* onb = (const float*)d_in[33];
  float* out = (float*)d_out;

  char* p = (char*)d_ws;
  auto alloc = [&](size_t n) { void* r = (void*)p; p += (n + 255) & ~(size_t)255; return r; };

  unsigned short* wqkvt = (unsigned short*)alloc((size_t)3 * HID * HID * 2);  // 2304 x 768
  unsigned short* wot   = (unsigned short*)alloc((size_t)HID * HID * 2);
  unsigned short* w1t   = (unsigned short*)alloc((size_t)FFND * HID * 2);
  unsigned short* w2t   = (unsigned short*)alloc((size_t)HID * FFND * 2);
  unsigned short* pqkvt = (unsigned short*)alloc((size_t)3 * HID * HID * 2);
  unsigned short* pwot  = (unsigned short*)alloc((size_t)HID * 2 * HID * 2);
  unsigned short* pjwt  = (unsigned short*)alloc((size_t)EOUTD * HID * 2);
  float*          qkvbias = (float*)alloc((size_t)3 * HID * 4);
  float*          pqkvbias= (float*)alloc((size_t)3 * HID * 4);
  unsigned short* bfA   = (unsigned short*)alloc((size_t)TOK * HID * 2);      // h1 -> h -> x3
  unsigned short* QKVb  = (unsigned short*)alloc((size_t)TOK * 3 * HID * 2);  // 65536 x 2304; FFN hidden alias
  unsigned short* bfB   = (unsigned short*)alloc((size_t)TOK * HID * 2);      // attn out
  unsigned short* x2b   = (unsigned short*)alloc((size_t)TOK * HID * 2);      // x2 (bf16)
  unsigned short* fusedb= (unsigned short*)alloc((size_t)BATCH * 2 * HID * 2);
  float*          qresb = (float*)alloc((size_t)BATCH * HID * 4);
  float*          preln = (float*)alloc((size_t)BATCH * HID * 4);
  unsigned short* pooledb=(unsigned short*)alloc((size_t)BATCH * HID * 2);
  float*          news  = (float*)alloc((size_t)BATCH * EOUTD * 4);
  (void)ws_size; (void)in_sizes; (void)n_in; (void)out_size;

  // fused weight prep (was 13 launches)
  prep_k<<<10002, 256, 0, stream>>>(
      wq, wk, wv, wo, w1, w2, pwq, pwk, pwv, pwo, pjw,
      wqkvt, wot, w1t, w2t, pqkvt, pwot, pjwt,
      bq, bk, bv, pbq, pbk, pbv, qkvbias, pqkvbias);

  // LN1
  ln768_k<<<TOK, 256, 0, stream>>>(x, n1g, n1b, bfA);

  // fused QKV GEMM: 65536 x 2304, K=768  [128^2, proven]
  gemm_k<EPI_OUTB><<<(TOK/128)*(3*HID/128), 256, 0, stream>>>(
      bfA, wqkvt, qkvbias, nullptr, nullptr, nullptr, QKVb, TOK, 3*HID, HID);

  // fastformer attention -> bfB (stride 768)
  fastattn2_k<false><<<BATCH * NHEAD / 4, 256, 0, stream>>>(
      QKVb, QKVb + HID, QKVb + 2*HID, 3*HID, mask, bfB, nullptr, nullptr);

  // wo proj + f32 resid x -> x2 (bf16)   [128^2]
  gemm_k<EPI_OUTB | EPI_RESF><<<(TOK/128)*(HID/128), 256, 0, stream>>>(
      bfB, wot, bo, x, nullptr, nullptr, x2b, TOK, HID, HID);

  // LN2 (bf16 in)
  ln768b_k<<<TOK, 256, 0, stream>>>(x2b, n2g, n2b, bfA);

  // FFN in 2 row-chunks of 32768; hidden lives in QKVb (dead until pool QKV)  [128^2]
  for (int c = 0; c < 2; c++) {
    const size_t ro = (size_t)c * 32768;
    gemm_k<EPI_OUTB | EPI_GELU><<<(32768/128)*(FFND/128), 256, 0, stream>>>(
        bfA + ro * HID, w1t, b1, nullptr, nullptr, nullptr, QKVb, 32768, FFND, HID);
    gemm_k<EPI_OUTB | EPI_RESB><<<(32768/128)*(HID/128), 256, 0, stream>>>(
        QKVb, w2t, b2, nullptr, x2b + ro * HID, nullptr, bfA + ro * HID, 32768, HID, FFND);
  }
  // bfA = x3 (bf16)

  // fused pool QKV GEMM  [128^2]
  gemm_k<EPI_OUTB><<<(TOK/128)*(3*HID/128), 256, 0, stream>>>(
      bfA, pqkvt, pqkvbias, nullptr, nullptr, nullptr, QKVb, TOK, 3*HID, HID);

  // pooling core
  fastattn2_k<true><<<BATCH * NHEAD / 4, 256, 0, stream>>>(
      QKVb, QKVb + HID, QKVb + 2*HID, 3*HID, mask, nullptr, fusedb, qresb);

  // pool out proj (+qres) -> preln f32  [128^2]
  gemm_k<EPI_OUTF | EPI_RESF><<<(BATCH/128)*(HID/128), 256, 0, stream>>>(
      fusedb, pwot, pbo, qresb, nullptr, preln, nullptr, BATCH, HID, 2*HID);

  // double LN -> pooled bf16
  ln2x_k<<<BATCH, 256, 0, stream>>>(preln, png, pnb, tng, tnb, pooledb);

  // proj -> news f32  [128^2]
  gemm_k<EPI_OUTF><<<(BATCH/128)*(EOUTD/128), 256, 0, stream>>>(
      pooledb, pjwt, pjb, nullptr, nullptr, news, nullptr, BATCH, EOUTD, HID);

  // final LN
  lnf_k<<<BATCH, 256, 0, stream>>>(news, ong, onb, out);
}